// Round 1
// baseline (760.165 us; speedup 1.0000x reference)
//
#include <hip/hip_runtime.h>
#include <hip/hip_bf16.h>
#include <cstdint>
#include <cstddef>

typedef __bf16 bf16;
typedef bf16 bf16x8 __attribute__((ext_vector_type(8)));
typedef float f32x4 __attribute__((ext_vector_type(4)));

#define HEAD_DIM 256
#define NHEADS 8
#define NKV 4
#define BATCH 2
#define SEQ 2048
#define IND 5120
#define HID 2560
#define ROWS (BATCH*SEQ)   // 4096
#define NQKV 4096          // 2048 + 1024 + 1024

__device__ __forceinline__ f32x4 mfma16(bf16x8 a, bf16x8 b, f32x4 c) {
  return __builtin_amdgcn_mfma_f32_16x16x32_bf16(a, b, c, 0, 0, 0);
}

// ---------------- cast fp32 -> bf16, 8 elements/thread ----------------
__global__ void cast8(const float* __restrict__ in, bf16* __restrict__ out, int n) {
  int i = (blockIdx.x * 256 + threadIdx.x) * 8;
  if (i >= n) return;
  float4 a = *(const float4*)(in + i);
  float4 b = *(const float4*)(in + i + 4);
  bf16x8 o;
  o[0] = (bf16)a.x; o[1] = (bf16)a.y; o[2] = (bf16)a.z; o[3] = (bf16)a.w;
  o[4] = (bf16)b.x; o[5] = (bf16)b.y; o[6] = (bf16)b.z; o[7] = (bf16)b.w;
  *(bf16x8*)(out + i) = o;
}

// ---------------- BT GEMM: C[m,n] = sum_k A[m,k] * B[n,k] ----------------
// 128x128 tile, BK=64, 4 waves (2x2), each wave 64x64 via 4x4 16x16x32 frags.
template<typename OutT>
__global__ __launch_bounds__(256) void gemm_bt(const bf16* __restrict__ A,
                                               const bf16* __restrict__ B,
                                               OutT* __restrict__ C,
                                               int M, int N, int K) {
  __shared__ bf16 sA[128 * 64];
  __shared__ bf16 sB[128 * 64];
  const int tid = threadIdx.x;
  const int lane = tid & 63;
  const int w = tid >> 6;
  const int wm = w >> 1, wn = w & 1;
  const int m0 = blockIdx.y * 128, n0 = blockIdx.x * 128;
  const int l15 = lane & 15, lg = lane >> 4;
  f32x4 acc[4][4] = {};
  for (int k0 = 0; k0 < K; k0 += 64) {
    __syncthreads();  // protect LDS reuse from previous iteration reads
    for (int i = 0; i < 4; ++i) {
      int c = i * 256 + tid;          // chunk id: uniform part + lane -> LDS = base + lane*16
      int row = c >> 3, kk = (c & 7) * 8;
      __builtin_amdgcn_global_load_lds(
          (const __attribute__((address_space(1))) void*)(A + (size_t)(m0 + row) * K + k0 + kk),
          (__attribute__((address_space(3))) void*)(sA + c * 8), 16, 0, 0);
      __builtin_amdgcn_global_load_lds(
          (const __attribute__((address_space(1))) void*)(B + (size_t)(n0 + row) * K + k0 + kk),
          (__attribute__((address_space(3))) void*)(sB + c * 8), 16, 0, 0);
    }
    __syncthreads();  // drains vmcnt before use
    bf16x8 af[2][4], bfr[2][4];
    for (int kc = 0; kc < 2; ++kc)
      for (int i = 0; i < 4; ++i) {
        af[kc][i]  = *(const bf16x8*)&sA[(wm * 64 + i * 16 + l15) * 64 + kc * 32 + lg * 8];
        bfr[kc][i] = *(const bf16x8*)&sB[(wn * 64 + i * 16 + l15) * 64 + kc * 32 + lg * 8];
      }
    for (int kc = 0; kc < 2; ++kc)
      for (int mi = 0; mi < 4; ++mi)
        for (int ni = 0; ni < 4; ++ni)
          acc[mi][ni] = mfma16(af[kc][mi], bfr[kc][ni], acc[mi][ni]);
  }
  for (int mi = 0; mi < 4; ++mi)
    for (int ni = 0; ni < 4; ++ni) {
      int row = m0 + wm * 64 + mi * 16 + lg * 4;
      int col = n0 + wn * 64 + ni * 16 + l15;
      for (int r = 0; r < 4; ++r)
        C[(size_t)(row + r) * N + col] = (OutT)acc[mi][ni][r];
    }
}

// ---------------- RoPE + reorder into Q (B,H,S,D) and K (B,KV,S,D) ----------------
__global__ void rope_reorder(const bf16* __restrict__ QKV,
                             bf16* __restrict__ Qr, bf16* __restrict__ Kr) {
  const int row = blockIdx.x;   // b*SEQ + s
  const int slot = blockIdx.y;  // 0..7 q heads, 8..11 k heads
  const int d = threadIdx.x;    // 0..127
  const int b = row >> 11, s = row & 2047;
  const bool isq = slot < 8;
  const int col0 = isq ? slot * HEAD_DIM : 2048 + (slot - 8) * HEAD_DIM;
  float x1 = (float)QKV[(size_t)row * NQKV + col0 + d];
  float x2 = (float)QKV[(size_t)row * NQKV + col0 + d + 128];
  float invf = exp2f((float)d * (-13.287712379549449f / 128.0f)); // 10000^(-d/128)
  float fr = (float)s * invf;
  float sn, cs;
  sincosf(fr, &sn, &cs);
  bf16* dst = isq ? (Qr + ((size_t)(b * NHEADS + slot) * SEQ + s) * HEAD_DIM)
                  : (Kr + ((size_t)(b * NKV + (slot - 8)) * SEQ + s) * HEAD_DIM);
  dst[d]       = (bf16)(x1 * cs - x2 * sn);
  dst[d + 128] = (bf16)(x2 * cs + x1 * sn);
}

// ---------------- V transpose: VT[bkv][d][s] = QKV[b*S+s][3072 + kv*256 + d] ----------------
__global__ void v_transpose(const bf16* __restrict__ QKV, bf16* __restrict__ VT) {
  __shared__ bf16 tile[64][66];
  const int bkv = blockIdx.y;            // b*NKV + kv
  const int b = bkv >> 2, kv = bkv & 3;
  const int st = blockIdx.x & 31, dt = blockIdx.x >> 5;
  const int s0 = st * 64, d0 = dt * 64;
  const int tj = threadIdx.x & 63, ti = threadIdx.x >> 6;
  for (int i = ti; i < 64; i += 4)
    tile[i][tj] = QKV[(size_t)(b * SEQ + s0 + i) * NQKV + 3072 + kv * HEAD_DIM + d0 + tj];
  __syncthreads();
  for (int i = ti; i < 64; i += 4)
    VT[((size_t)bkv * HEAD_DIM + d0 + i) * SEQ + s0 + tj] = tile[tj][i];
}

// ---------------- flash attention, causal, per-wave 16 q-rows ----------------
__global__ __launch_bounds__(256) void flash_attn(const bf16* __restrict__ Q,
                                                  const bf16* __restrict__ Kp,
                                                  const bf16* __restrict__ VT,
                                                  bf16* __restrict__ AO) {
  __shared__ bf16 pbuf[4][16][72];
  const int tid = threadIdx.x, lane = tid & 63, w = tid >> 6;
  const int l15 = lane & 15, lg = lane >> 4;
  const int bh = blockIdx.x, qt = blockIdx.y;
  const int b = bh >> 3, h = bh & 7, kvh = h >> 1;
  const int q0 = qt * 64 + w * 16;
  const bf16* Qb = Q + ((size_t)bh * SEQ + q0) * HEAD_DIM;
  const bf16* Kb = Kp + ((size_t)(b * NKV + kvh) * SEQ) * HEAD_DIM;
  const bf16* Vb = VT + ((size_t)(b * NKV + kvh) * HEAD_DIM) * SEQ;

  bf16x8 qf[8];
  for (int dc = 0; dc < 8; ++dc)
    qf[dc] = *(const bf16x8*)&Qb[l15 * HEAD_DIM + dc * 32 + lg * 8];

  f32x4 oacc[16] = {};
  float mrow[4] = {-1e30f, -1e30f, -1e30f, -1e30f};
  float lrow[4] = {0.f, 0.f, 0.f, 0.f};

  for (int kb = 0; kb <= qt; ++kb) {
    const int kbase = kb * 64;
    // ---- S = Q K^T (16 x 64) ----
    f32x4 sacc[4] = {};
    for (int j = 0; j < 4; ++j) {
      const bf16* Kj = &Kb[(size_t)(kbase + j * 16 + l15) * HEAD_DIM + lg * 8];
      for (int dc = 0; dc < 8; ++dc) {
        bf16x8 kf = *(const bf16x8*)&Kj[dc * 32];
        sacc[j] = mfma16(qf[dc], kf, sacc[j]);
      }
    }
    // ---- mask + scale ----
    float sv[4][4];
    for (int j = 0; j < 4; ++j) {
      int scol = kbase + j * 16 + l15;
      for (int r = 0; r < 4; ++r) {
        int srow = q0 + lg * 4 + r;
        float v = sacc[j][r] * 0.0625f;  // 1/sqrt(256)
        sv[j][r] = (scol <= srow) ? v : -1e30f;
      }
    }
    // ---- online softmax (row-reduce across 16-lane groups) ----
    for (int r = 0; r < 4; ++r) {
      float mx = fmaxf(fmaxf(sv[0][r], sv[1][r]), fmaxf(sv[2][r], sv[3][r]));
      mx = fmaxf(mx, __shfl_xor(mx, 1));
      mx = fmaxf(mx, __shfl_xor(mx, 2));
      mx = fmaxf(mx, __shfl_xor(mx, 4));
      mx = fmaxf(mx, __shfl_xor(mx, 8));
      float mnew = fmaxf(mrow[r], mx);
      float alpha = __expf(mrow[r] - mnew);
      mrow[r] = mnew;
      float sum = 0.f;
      for (int j = 0; j < 4; ++j) {
        float e = __expf(sv[j][r] - mnew);
        sv[j][r] = e;
        sum += e;
      }
      sum += __shfl_xor(sum, 1);
      sum += __shfl_xor(sum, 2);
      sum += __shfl_xor(sum, 4);
      sum += __shfl_xor(sum, 8);
      lrow[r] = lrow[r] * alpha + sum;
      for (int ni = 0; ni < 16; ++ni) oacc[ni][r] *= alpha;
    }
    // ---- P -> LDS (transpose to A-fragment layout) ----
    for (int j = 0; j < 4; ++j)
      for (int r = 0; r < 4; ++r)
        pbuf[w][lg * 4 + r][j * 16 + l15] = (bf16)sv[j][r];
    bf16x8 pa0 = *(const bf16x8*)&pbuf[w][l15][lg * 8];
    bf16x8 pa1 = *(const bf16x8*)&pbuf[w][l15][32 + lg * 8];
    // ---- O += P V  (V stored transposed: BT form) ----
    for (int ni = 0; ni < 16; ++ni) {
      const bf16* Vp = &Vb[(size_t)(ni * 16 + l15) * SEQ + kbase + lg * 8];
      bf16x8 v0 = *(const bf16x8*)&Vp[0];
      bf16x8 v1 = *(const bf16x8*)&Vp[32];
      oacc[ni] = mfma16(pa0, v0, oacc[ni]);
      oacc[ni] = mfma16(pa1, v1, oacc[ni]);
    }
  }
  float inv[4];
  for (int r = 0; r < 4; ++r) inv[r] = 1.0f / lrow[r];
  bf16* Ob = AO + ((size_t)(b * SEQ + q0)) * 2048 + h * HEAD_DIM;
  for (int ni = 0; ni < 16; ++ni)
    for (int r = 0; r < 4; ++r)
      Ob[(size_t)(lg * 4 + r) * 2048 + ni * 16 + l15] = (bf16)(oacc[ni][r] * inv[r]);
}

// ---------------- launch ----------------
extern "C" void kernel_launch(void* const* d_in, const int* in_sizes, int n_in,
                              void* d_out, int out_size, void* d_ws, size_t ws_size,
                              hipStream_t stream) {
  const float* hs = (const float*)d_in[0];
  // d_in[1] = attention_mask (causal, applied analytically), d_in[2] = position_ids (arange)
  const float* Wq = (const float*)d_in[3];
  const float* Wk = (const float*)d_in[4];
  const float* Wv = (const float*)d_in[5];
  const float* Wo = (const float*)d_in[6];
  float* out = (float*)d_out;

  char* ws = (char*)d_ws;
  bf16* hsb  = (bf16*)(ws);                    // 4096x5120        (41,943,040 B)
  bf16* wqkv = (bf16*)(ws + 41943040);         // 4096x5120        (41,943,040 B)
  bf16* qkv  = (bf16*)(ws + 83886080);         // 4096x4096        (33,554,432 B)
  bf16* qr   = (bf16*)(ws + 117440512);        // 2x8x2048x256     (16,777,216 B)
  bf16* kr   = (bf16*)(ws + 134217728);        // 2x4x2048x256     ( 8,388,608 B)
  bf16* vt   = (bf16*)(ws + 142606336);        // 2x4x256x2048     ( 8,388,608 B)
  bf16* ao   = (bf16*)(ws + 150994944);        // 4096x2048        (16,777,216 B)
  bf16* wob  = (bf16*)(ws + 167772160);        // 2560x2048        (10,485,760 B)

  // casts
  cast8<<<ROWS * IND / 2048, 256, 0, stream>>>(hs, hsb, ROWS * IND);
  cast8<<<2048 * IND / 2048, 256, 0, stream>>>(Wq, wqkv, 2048 * IND);
  cast8<<<1024 * IND / 2048, 256, 0, stream>>>(Wk, wqkv + 2048 * IND, 1024 * IND);
  cast8<<<1024 * IND / 2048, 256, 0, stream>>>(Wv, wqkv + 3072 * IND, 1024 * IND);
  cast8<<<HID * 2048 / 2048, 256, 0, stream>>>(Wo, wob, HID * 2048);

  // QKV projection: (4096 x 5120) @ (4096 x 5120)^T -> (4096 x 4096)
  gemm_bt<bf16><<<dim3(NQKV / 128, ROWS / 128), 256, 0, stream>>>(hsb, wqkv, qkv, ROWS, NQKV, IND);

  // RoPE + reorder, V transpose
  rope_reorder<<<dim3(ROWS, 12), 128, 0, stream>>>(qkv, qr, kr);
  v_transpose<<<dim3(128, BATCH * NKV), 256, 0, stream>>>(qkv, vt);

  // flash attention
  flash_attn<<<dim3(BATCH * NHEADS, SEQ / 64), 256, 0, stream>>>(qr, kr, vt, ao);

  // output projection: (4096 x 2048) @ (2560 x 2048)^T -> (4096 x 2560) fp32
  gemm_bt<float><<<dim3(HID / 128, ROWS / 128), 256, 0, stream>>>(ao, wob, out, ROWS, HID, 2048);
}

// Round 2
// 576.865 us; speedup vs baseline: 1.3178x; 1.3178x over previous
//
#include <hip/hip_runtime.h>
#include <hip/hip_bf16.h>
#include <cstdint>
#include <cstddef>

typedef __bf16 bf16;
typedef bf16 bf16x4 __attribute__((ext_vector_type(4)));
typedef bf16 bf16x8 __attribute__((ext_vector_type(8)));
typedef float f32x4 __attribute__((ext_vector_type(4)));

#define HEAD_DIM 256
#define NHEADS 8
#define NKV 4
#define BATCH 2
#define SEQ 2048
#define IND 5120
#define HID 2560
#define ROWS (BATCH*SEQ)   // 4096
#define NQKV 4096          // 2048 + 1024 + 1024
#define CHUNKS_PER_BH 80   // sum over qt of ceil((qt+1)/8)

__device__ __forceinline__ f32x4 mfma16(bf16x8 a, bf16x8 b, f32x4 c) {
  return __builtin_amdgcn_mfma_f32_16x16x32_bf16(a, b, c, 0, 0, 0);
}

// ---------------- cast fp32 -> bf16, 8 elements/thread ----------------
__global__ void cast8(const float* __restrict__ in, bf16* __restrict__ out, int n) {
  int i = (blockIdx.x * 256 + threadIdx.x) * 8;
  if (i >= n) return;
  float4 a = *(const float4*)(in + i);
  float4 b = *(const float4*)(in + i + 4);
  bf16x8 o;
  o[0] = (bf16)a.x; o[1] = (bf16)a.y; o[2] = (bf16)a.z; o[3] = (bf16)a.w;
  o[4] = (bf16)b.x; o[5] = (bf16)b.y; o[6] = (bf16)b.z; o[7] = (bf16)b.w;
  *(bf16x8*)(out + i) = o;
}

// ---------------- BT GEMM: C[m,n] = sum_k A[m,k] * B[n,k] ----------------
template<typename OutT>
__global__ __launch_bounds__(256) void gemm_bt(const bf16* __restrict__ A,
                                               const bf16* __restrict__ B,
                                               OutT* __restrict__ C,
                                               int M, int N, int K) {
  __shared__ bf16 sA[128 * 64];
  __shared__ bf16 sB[128 * 64];
  const int tid = threadIdx.x;
  const int lane = tid & 63;
  const int w = tid >> 6;
  const int wm = w >> 1, wn = w & 1;
  // XCD-aware swizzle (T1): nwg % 8 == 0 for all our launches
  const int gx = gridDim.x;
  const int id = blockIdx.y * gx + blockIdx.x;
  const int cpx = (gx * gridDim.y) >> 3;
  const int nid = (id & 7) * cpx + (id >> 3);
  const int m0 = (nid / gx) * 128, n0 = (nid % gx) * 128;
  const int l15 = lane & 15, lg = lane >> 4;
  f32x4 acc[4][4] = {};
  for (int k0 = 0; k0 < K; k0 += 64) {
    __syncthreads();
    for (int i = 0; i < 4; ++i) {
      int c = i * 256 + tid;
      int row = c >> 3, kk = (c & 7) * 8;
      __builtin_amdgcn_global_load_lds(
          (const __attribute__((address_space(1))) void*)(A + (size_t)(m0 + row) * K + k0 + kk),
          (__attribute__((address_space(3))) void*)(sA + c * 8), 16, 0, 0);
      __builtin_amdgcn_global_load_lds(
          (const __attribute__((address_space(1))) void*)(B + (size_t)(n0 + row) * K + k0 + kk),
          (__attribute__((address_space(3))) void*)(sB + c * 8), 16, 0, 0);
    }
    __syncthreads();
    bf16x8 af[2][4], bfr[2][4];
    for (int kc = 0; kc < 2; ++kc)
      for (int i = 0; i < 4; ++i) {
        af[kc][i]  = *(const bf16x8*)&sA[(wm * 64 + i * 16 + l15) * 64 + kc * 32 + lg * 8];
        bfr[kc][i] = *(const bf16x8*)&sB[(wn * 64 + i * 16 + l15) * 64 + kc * 32 + lg * 8];
      }
    for (int kc = 0; kc < 2; ++kc)
      for (int mi = 0; mi < 4; ++mi)
        for (int ni = 0; ni < 4; ++ni)
          acc[mi][ni] = mfma16(af[kc][mi], bfr[kc][ni], acc[mi][ni]);
  }
  for (int mi = 0; mi < 4; ++mi)
    for (int ni = 0; ni < 4; ++ni) {
      int row = m0 + wm * 64 + mi * 16 + lg * 4;
      int col = n0 + wn * 64 + ni * 16 + l15;
      for (int r = 0; r < 4; ++r)
        C[(size_t)(row + r) * N + col] = (OutT)acc[mi][ni][r];
    }
}

// ---------------- RoPE + reorder into Q (B,H,S,D) and K (B,KV,S,D) ----------------
__global__ void rope_reorder(const bf16* __restrict__ QKV,
                             bf16* __restrict__ Qr, bf16* __restrict__ Kr) {
  const int row = blockIdx.x;   // b*SEQ + s
  const int slot = blockIdx.y;  // 0..7 q heads, 8..11 k heads
  const int d = threadIdx.x;    // 0..127
  const int b = row >> 11, s = row & 2047;
  const bool isq = slot < 8;
  const int col0 = isq ? slot * HEAD_DIM : 2048 + (slot - 8) * HEAD_DIM;
  float x1 = (float)QKV[(size_t)row * NQKV + col0 + d];
  float x2 = (float)QKV[(size_t)row * NQKV + col0 + d + 128];
  float invf = exp2f((float)d * (-13.287712379549449f / 128.0f)); // 10000^(-d/128)
  float fr = (float)s * invf;
  float sn, cs;
  sincosf(fr, &sn, &cs);
  bf16* dst = isq ? (Qr + ((size_t)(b * NHEADS + slot) * SEQ + s) * HEAD_DIM)
                  : (Kr + ((size_t)(b * NKV + (slot - 8)) * SEQ + s) * HEAD_DIM);
  dst[d]       = (bf16)(x1 * cs - x2 * sn);
  dst[d + 128] = (bf16)(x2 * cs + x1 * sn);
}

// ---------------- V transpose: VT[bkv][d][s] ----------------
__global__ void v_transpose(const bf16* __restrict__ QKV, bf16* __restrict__ VT) {
  __shared__ bf16 tile[64][66];
  const int bkv = blockIdx.y;
  const int b = bkv >> 2, kv = bkv & 3;
  const int st = blockIdx.x & 31, dt = blockIdx.x >> 5;
  const int s0 = st * 64, d0 = dt * 64;
  const int tj = threadIdx.x & 63, ti = threadIdx.x >> 6;
  for (int i = ti; i < 64; i += 4)
    tile[i][tj] = QKV[(size_t)(b * SEQ + s0 + i) * NQKV + 3072 + kv * HEAD_DIM + d0 + tj];
  __syncthreads();
  for (int i = ti; i < 64; i += 4)
    VT[((size_t)bkv * HEAD_DIM + d0 + i) * SEQ + s0 + tj] = tile[tj][i];
}

// ---------------- flash attention v2: chunked KV, swapped QK^T, LDS-staged K/V ----
// grid.x = 16 bh * 80 chunks = 1280. Each block: 4 waves, 64 q-rows (16/wave),
// processes KV blocks [kb0, kb1) of its q-tile; writes unnormalized partial O + (m,l).
__global__ __launch_bounds__(256) void flash_attn(const bf16* __restrict__ Q,
                                                  const bf16* __restrict__ Kp,
                                                  const bf16* __restrict__ VT,
                                                  bf16* __restrict__ Opart,
                                                  float* __restrict__ ML) {
  __shared__ bf16 Ks[64 * 256];   // [krow][d], 16B chunks XOR-swizzled by (krow&7)
  __shared__ bf16 Vs[256 * 64];   // [d][kv], 16B chunks XOR-swizzled by (d&7)
  __shared__ bf16 pbuf[4][16][80];

  const int tid = threadIdx.x, lane = tid & 63, w = tid >> 6;
  const int l15 = lane & 15, lg = lane >> 4;

  // ---- chunk decode ----
  const int cid = blockIdx.x;
  const int bh = cid / CHUNKS_PER_BH;
  const int c  = cid - bh * CHUNKS_PER_BH;
  int qt, ki;
  if (c < 8)       { qt = c;                 ki = 0; }
  else if (c < 24) { qt = 8  + ((c - 8) >> 1);  ki = (c - 8)  & 1; }
  else if (c < 48) { qt = 16 + (c - 24) / 3;    ki = (c - 24) % 3; }
  else             { qt = 24 + ((c - 48) >> 2); ki = (c - 48) & 3; }
  const int kb0 = ki * 8;
  const int kb1 = min(kb0 + 8, qt + 1);

  const int b = bh >> 3, h = bh & 7, kvh = h >> 1;
  const int bkv = b * NKV + kvh;
  const int q0 = qt * 64 + w * 16;

  // ---- Q fragments (B-operand: row = q = l15, k = d) ----
  const bf16* Qb = Q + ((size_t)bh * SEQ + q0) * HEAD_DIM;
  bf16x8 qf[8];
  #pragma unroll
  for (int dc = 0; dc < 8; ++dc)
    qf[dc] = *(const bf16x8*)&Qb[l15 * HEAD_DIM + dc * 32 + lg * 8];

  f32x4 oacc[16] = {};
  float m = -1e30f, l = 0.f;

  const bf16* Ksrc = Kp + (size_t)bkv * SEQ * HEAD_DIM;
  const bf16* Vsrc = VT + (size_t)bkv * HEAD_DIM * SEQ;

  for (int kb = kb0; kb < kb1; ++kb) {
    const int kbase = kb * 64;
    __syncthreads();   // previous iter's LDS reads done
    // ---- stage K (64x256) and V^T (256x64), pre-swizzled global source ----
    #pragma unroll
    for (int i = 0; i < 8; ++i) {
      int id = i * 256 + tid;
      int row = id >> 5, ch = id & 31;
      int sc = ch ^ (row & 7);
      __builtin_amdgcn_global_load_lds(
          (const __attribute__((address_space(1))) void*)(Ksrc + (size_t)(kbase + row) * HEAD_DIM + sc * 8),
          (__attribute__((address_space(3))) void*)(Ks + id * 8), 16, 0, 0);
    }
    #pragma unroll
    for (int i = 0; i < 8; ++i) {
      int id = i * 256 + tid;
      int row = id >> 3, ch = id & 7;
      int sc = ch ^ (row & 7);
      __builtin_amdgcn_global_load_lds(
          (const __attribute__((address_space(1))) void*)(Vsrc + (size_t)row * SEQ + kbase + sc * 8),
          (__attribute__((address_space(3))) void*)(Vs + id * 8), 16, 0, 0);
    }
    __syncthreads();   // staging complete

    // ---- S^T = K Q^T: lane holds q-row = l15, kcols {j*16 + lg*4 + r} ----
    f32x4 sacc[4] = {};
    #pragma unroll
    for (int j = 0; j < 4; ++j) {
      const bf16* kl = &Ks[(j * 16 + l15) * HEAD_DIM];
      #pragma unroll
      for (int dc = 0; dc < 8; ++dc) {
        int ch = (dc * 4 + lg) ^ (l15 & 7);
        bf16x8 kf = *(const bf16x8*)&kl[ch * 8];
        sacc[j] = mfma16(kf, qf[dc], sacc[j]);
      }
    }

    // ---- mask + scale (wave-uniform skip when fully unmasked) ----
    float px[4][4];
    const bool need_mask = (kbase + 63 > q0);
    #pragma unroll
    for (int j = 0; j < 4; ++j)
      #pragma unroll
      for (int r = 0; r < 4; ++r) {
        float v = sacc[j][r] * 0.0625f;   // 1/sqrt(256)
        if (need_mask) {
          int kcol = kbase + j * 16 + lg * 4 + r;
          v = (kcol <= q0 + l15) ? v : -1e30f;
        }
        px[j][r] = v;
      }

    // ---- online softmax: in-lane 16-value reduce + 2 shfls ----
    float mx = px[0][0];
    #pragma unroll
    for (int j = 0; j < 4; ++j)
      #pragma unroll
      for (int r = 0; r < 4; ++r) mx = fmaxf(mx, px[j][r]);
    mx = fmaxf(mx, __shfl_xor(mx, 16));
    mx = fmaxf(mx, __shfl_xor(mx, 32));
    float mnew = fmaxf(m, mx);
    float alpha = __expf(m - mnew);
    m = mnew;
    float s = 0.f;
    #pragma unroll
    for (int j = 0; j < 4; ++j) {
      bf16x4 pk;
      #pragma unroll
      for (int r = 0; r < 4; ++r) {
        float e = __expf(px[j][r] - mnew);
        s += e;
        pk[r] = (bf16)e;
      }
      *(bf16x4*)&pbuf[w][l15][j * 16 + lg * 4] = pk;
    }
    s += __shfl_xor(s, 16);
    s += __shfl_xor(s, 32);
    l = l * alpha + s;

    // ---- rescale O (alpha lives in q=l15 layout; oacc rows are q=lg*4+r) ----
    float ar[4];
    #pragma unroll
    for (int r = 0; r < 4; ++r) ar[r] = __shfl(alpha, lg * 4 + r);
    #pragma unroll
    for (int ni = 0; ni < 16; ++ni)
      #pragma unroll
      for (int r = 0; r < 4; ++r) oacc[ni][r] *= ar[r];

    // ---- P fragments from LDS, O += P V ----
    bf16x8 pa0 = *(const bf16x8*)&pbuf[w][l15][lg * 8];
    bf16x8 pa1 = *(const bf16x8*)&pbuf[w][l15][32 + lg * 8];
    #pragma unroll
    for (int ni = 0; ni < 16; ++ni) {
      const bf16* vb = &Vs[(ni * 16 + l15) * 64];
      int c0 = lg ^ (l15 & 7);
      int c1 = (4 + lg) ^ (l15 & 7);
      bf16x8 v0 = *(const bf16x8*)&vb[c0 * 8];
      bf16x8 v1 = *(const bf16x8*)&vb[c1 * 8];
      oacc[ni] = mfma16(pa0, v0, oacc[ni]);
      oacc[ni] = mfma16(pa1, v1, oacc[ni]);
    }
  }

  // ---- write unnormalized partial + (m,l) ----
  bf16* Ob = Opart + ((size_t)cid * 64 + w * 16) * HEAD_DIM;
  #pragma unroll
  for (int ni = 0; ni < 16; ++ni)
    #pragma unroll
    for (int r = 0; r < 4; ++r)
      Ob[(size_t)(lg * 4 + r) * HEAD_DIM + ni * 16 + l15] = (bf16)oacc[ni][r];
  if (lg == 0) {
    ML[((size_t)cid * 64 + w * 16 + l15) * 2]     = m;
    ML[((size_t)cid * 64 + w * 16 + l15) * 2 + 1] = l;
  }
}

// ---------------- merge partials -> ao (b, s, h*256+d) bf16 ----------------
__global__ __launch_bounds__(256) void flash_merge(const bf16* __restrict__ Opart,
                                                   const float* __restrict__ ML,
                                                   bf16* __restrict__ AO) {
  const int bh = blockIdx.x, qt = blockIdx.y;
  const int b = bh >> 3, h = bh & 7;
  int cbase, nc;
  if (qt < 8)       { cbase = qt;                nc = 1; }
  else if (qt < 16) { cbase = 8  + 2 * (qt - 8);  nc = 2; }
  else if (qt < 24) { cbase = 24 + 3 * (qt - 16); nc = 3; }
  else              { cbase = 48 + 4 * (qt - 24); nc = 4; }
  const int cid0 = bh * CHUNKS_PER_BH + cbase;

  const int tid = threadIdx.x;
  const int row = tid >> 2, dseg = (tid & 3) * 64;

  float mi[4], li[4];
  float M = -1e30f;
  for (int i = 0; i < nc; ++i) {
    mi[i] = ML[((size_t)(cid0 + i) * 64 + row) * 2];
    li[i] = ML[((size_t)(cid0 + i) * 64 + row) * 2 + 1];
    M = fmaxf(M, mi[i]);
  }
  float wgt[4], L = 0.f;
  for (int i = 0; i < nc; ++i) {
    wgt[i] = __expf(mi[i] - M);
    L += li[i] * wgt[i];
  }
  const float inv = 1.0f / L;

  bf16* dst = AO + ((size_t)(b * SEQ + qt * 64 + row)) * 2048 + h * HEAD_DIM + dseg;
  for (int dv = 0; dv < 8; ++dv) {
    float acc[8] = {};
    for (int i = 0; i < nc; ++i) {
      bf16x8 o = *(const bf16x8*)&Opart[((size_t)(cid0 + i) * 64 + row) * HEAD_DIM + dseg + dv * 8];
      #pragma unroll
      for (int e = 0; e < 8; ++e) acc[e] += wgt[i] * (float)o[e];
    }
    bf16x8 ov;
    #pragma unroll
    for (int e = 0; e < 8; ++e) ov[e] = (bf16)(acc[e] * inv);
    *(bf16x8*)&dst[dv * 8] = ov;
  }
}

// ---------------- launch ----------------
extern "C" void kernel_launch(void* const* d_in, const int* in_sizes, int n_in,
                              void* d_out, int out_size, void* d_ws, size_t ws_size,
                              hipStream_t stream) {
  const float* hs = (const float*)d_in[0];
  const float* Wq = (const float*)d_in[3];
  const float* Wk = (const float*)d_in[4];
  const float* Wv = (const float*)d_in[5];
  const float* Wo = (const float*)d_in[6];
  float* out = (float*)d_out;

  char* ws = (char*)d_ws;
  bf16* hsb  = (bf16*)(ws);                    // 4096x5120        (41,943,040 B)
  bf16* wqkv = (bf16*)(ws + 41943040);         // 4096x5120        (41,943,040 B)
  bf16* qkv  = (bf16*)(ws + 83886080);         // 4096x4096        (33,554,432 B)
  bf16* qr   = (bf16*)(ws + 117440512);        // 2x8x2048x256     (16,777,216 B)
  bf16* kr   = (bf16*)(ws + 134217728);        // 2x4x2048x256     ( 8,388,608 B)
  bf16* vt   = (bf16*)(ws + 142606336);        // 2x4x256x2048     ( 8,388,608 B)
  bf16* ao   = (bf16*)(ws + 150994944);        // 4096x2048        (16,777,216 B)
  bf16* wob  = (bf16*)(ws + 167772160);        // 2560x2048        (10,485,760 B)
  // flash partials overlay hsb/wqkv (dead after gemm1):
  bf16*  opart = (bf16*)(ws);                  // 1280x64x256 bf16 (41,943,040 B)
  float* ml    = (float*)(ws + 41943040);      // 1280x64x2  f32   (   655,360 B)

  cast8<<<ROWS * IND / 2048, 256, 0, stream>>>(hs, hsb, ROWS * IND);
  cast8<<<2048 * IND / 2048, 256, 0, stream>>>(Wq, wqkv, 2048 * IND);
  cast8<<<1024 * IND / 2048, 256, 0, stream>>>(Wk, wqkv + 2048 * IND, 1024 * IND);
  cast8<<<1024 * IND / 2048, 256, 0, stream>>>(Wv, wqkv + 3072 * IND, 1024 * IND);
  cast8<<<HID * 2048 / 2048, 256, 0, stream>>>(Wo, wob, HID * 2048);

  gemm_bt<bf16><<<dim3(NQKV / 128, ROWS / 128), 256, 0, stream>>>(hsb, wqkv, qkv, ROWS, NQKV, IND);

  rope_reorder<<<dim3(ROWS, 12), 128, 0, stream>>>(qkv, qr, kr);
  v_transpose<<<dim3(128, BATCH * NKV), 256, 0, stream>>>(qkv, vt);

  flash_attn<<<dim3(16 * CHUNKS_PER_BH), 256, 0, stream>>>(qr, kr, vt, opart, ml);
  flash_merge<<<dim3(16, 32), 256, 0, stream>>>(opart, ml, ao);

  gemm_bt<float><<<dim3(HID / 128, ROWS / 128), 256, 0, stream>>>(ao, wob, out, ROWS, HID, 2048);
}

// Round 3
// 443.901 us; speedup vs baseline: 1.7125x; 1.2995x over previous
//
#include <hip/hip_runtime.h>
#include <hip/hip_bf16.h>
#include <cstdint>
#include <cstddef>

typedef __bf16 bf16;
typedef bf16 bf16x4 __attribute__((ext_vector_type(4)));
typedef bf16 bf16x8 __attribute__((ext_vector_type(8)));
typedef float f32x4 __attribute__((ext_vector_type(4)));

#define HEAD_DIM 256
#define NHEADS 8
#define NKV 4
#define BATCH 2
#define SEQ 2048
#define IND 5120
#define HID 2560
#define ROWS (BATCH*SEQ)   // 4096
#define NQKV 4096          // 2048 + 1024 + 1024
#define CHUNKS_PER_BH 80   // sum over qt of ceil((qt+1)/8)

__device__ __forceinline__ f32x4 mfma16(bf16x8 a, bf16x8 b, f32x4 c) {
  return __builtin_amdgcn_mfma_f32_16x16x32_bf16(a, b, c, 0, 0, 0);
}

// ---------------- cast fp32 -> bf16, 8 elements/thread ----------------
__global__ void cast8(const float* __restrict__ in, bf16* __restrict__ out, int n) {
  int i = (blockIdx.x * 256 + threadIdx.x) * 8;
  if (i >= n) return;
  float4 a = *(const float4*)(in + i);
  float4 b = *(const float4*)(in + i + 4);
  bf16x8 o;
  o[0] = (bf16)a.x; o[1] = (bf16)a.y; o[2] = (bf16)a.z; o[3] = (bf16)a.w;
  o[4] = (bf16)b.x; o[5] = (bf16)b.y; o[6] = (bf16)b.z; o[7] = (bf16)b.w;
  *(bf16x8*)(out + i) = o;
}

// ---------------- pipelined BT GEMM: C[m,n] = sum_k A[m,k]*B[n,k] ----------------
// 256x256 tile, BK=32, 512 thr / 8 waves (2Mx4N), per-wave 128x64 out (acc[8][4]).
// 4-slot LDS ring (128 KiB dynamic), 3 K-tiles prefetched, counted vmcnt (never 0),
// raw s_barrier (no vmcnt drain), full XOR swizzle -> conflict-free ds_read_b128.
// Ledger: reads of slot s (tile t) complete before phase-A-end lgkmcnt(0)+barrier;
// stage of tile t+3 into slot s' (holding dead tile t-1) issues only after that
// barrier; arrival of tile t is guaranteed by vmcnt(8) + top-of-loop barrier.
template<typename OutT>
__global__ __launch_bounds__(512, 2) void gemm_pipe(const bf16* __restrict__ A,
                                                    const bf16* __restrict__ B,
                                                    OutT* __restrict__ C,
                                                    int M, int N, int K) {
  extern __shared__ bf16 smem[];  // 4 slots x (8192 A + 8192 B) bf16 = 128 KiB
  const int tid = threadIdx.x;
  const int lane = tid & 63, w = tid >> 6;
  const int wm = w >> 2, wn = w & 3;
  const int l15 = lane & 15, lg = lane >> 4;
  const int gx = gridDim.x;
  const int nwg = gx * gridDim.y;
  const int id = blockIdx.y * gx + blockIdx.x;
  const int nid = (id & 7) * (nwg >> 3) + (id >> 3);   // bijective: nwg % 8 == 0
  const int m0 = (nid / gx) * 256, n0 = (nid % gx) * 256;
  const int NT = K >> 5;

  auto stage = [&](int slot, int kt) {
    bf16* sl = smem + slot * 16384;
    #pragma unroll
    for (int i = 0; i < 2; ++i) {
      int cid = i * 512 + tid;
      int row = cid >> 2;
      int sch = (cid & 3) ^ (row & 3);
      __builtin_amdgcn_global_load_lds(
        (const __attribute__((address_space(1))) void*)(A + (size_t)(m0 + row) * K + kt * 32 + sch * 8),
        (__attribute__((address_space(3))) void*)(sl + cid * 8), 16, 0, 0);
    }
    #pragma unroll
    for (int i = 0; i < 2; ++i) {
      int cid = i * 512 + tid;
      int row = cid >> 2;
      int sch = (cid & 3) ^ (row & 3);
      __builtin_amdgcn_global_load_lds(
        (const __attribute__((address_space(1))) void*)(B + (size_t)(n0 + row) * K + kt * 32 + sch * 8),
        (__attribute__((address_space(3))) void*)(sl + 8192 + cid * 8), 16, 0, 0);
    }
  };

  stage(0, 0); stage(1, 1); stage(2, 2);   // 12 loads in flight

  f32x4 acc[8][4] = {};
  for (int t = 0; t < NT; ++t) {
    asm volatile("s_waitcnt vmcnt(8)" ::: "memory");   // tile t fully in LDS
    __builtin_amdgcn_s_barrier();
    const bf16* sl = smem + (t & 3) * 16384;
    bf16x8 a[8], b[4];
    #pragma unroll
    for (int mi = 0; mi < 8; ++mi) {
      int row = wm * 128 + mi * 16 + l15;
      a[mi] = *(const bf16x8*)&sl[(row * 4 + (lg ^ (row & 3))) * 8];
    }
    #pragma unroll
    for (int ni = 0; ni < 4; ++ni) {
      int row = wn * 64 + ni * 16 + l15;
      b[ni] = *(const bf16x8*)&sl[8192 + (row * 4 + (lg ^ (row & 3))) * 8];
    }
    __builtin_amdgcn_s_setprio(1);
    #pragma unroll
    for (int ni = 0; ni < 2; ++ni)
      #pragma unroll
      for (int mi = 0; mi < 8; ++mi)
        acc[mi][ni] = mfma16(a[mi], b[ni], acc[mi][ni]);
    __builtin_amdgcn_s_setprio(0);
    asm volatile("s_waitcnt lgkmcnt(0)" ::: "memory"); // all slot reads complete
    __builtin_amdgcn_s_barrier();
    int kt = t + 3; if (kt > NT - 1) kt = NT - 1;      // tail: re-stage into dead slot
    stage((t + 3) & 3, kt);
    __builtin_amdgcn_s_setprio(1);
    #pragma unroll
    for (int ni = 2; ni < 4; ++ni)
      #pragma unroll
      for (int mi = 0; mi < 8; ++mi)
        acc[mi][ni] = mfma16(a[mi], b[ni], acc[mi][ni]);
    __builtin_amdgcn_s_setprio(0);
  }

  #pragma unroll
  for (int mi = 0; mi < 8; ++mi)
    #pragma unroll
    for (int ni = 0; ni < 4; ++ni) {
      int row = m0 + wm * 128 + mi * 16 + lg * 4;
      int col = n0 + wn * 64 + ni * 16 + l15;
      #pragma unroll
      for (int r = 0; r < 4; ++r)
        C[(size_t)(row + r) * N + col] = (OutT)acc[mi][ni][r];
    }
}

// ---------------- RoPE + reorder into Q (B,H,S,D) and K (B,KV,S,D) ----------------
__global__ void rope_reorder(const bf16* __restrict__ QKV,
                             bf16* __restrict__ Qr, bf16* __restrict__ Kr) {
  const int row = blockIdx.x;   // b*SEQ + s
  const int slot = blockIdx.y;  // 0..7 q heads, 8..11 k heads
  const int d = threadIdx.x;    // 0..127
  const int b = row >> 11, s = row & 2047;
  const bool isq = slot < 8;
  const int col0 = isq ? slot * HEAD_DIM : 2048 + (slot - 8) * HEAD_DIM;
  float x1 = (float)QKV[(size_t)row * NQKV + col0 + d];
  float x2 = (float)QKV[(size_t)row * NQKV + col0 + d + 128];
  float invf = exp2f((float)d * (-13.287712379549449f / 128.0f)); // 10000^(-d/128)
  float fr = (float)s * invf;
  float sn, cs;
  sincosf(fr, &sn, &cs);
  bf16* dst = isq ? (Qr + ((size_t)(b * NHEADS + slot) * SEQ + s) * HEAD_DIM)
                  : (Kr + ((size_t)(b * NKV + (slot - 8)) * SEQ + s) * HEAD_DIM);
  dst[d]       = (bf16)(x1 * cs - x2 * sn);
  dst[d + 128] = (bf16)(x2 * cs + x1 * sn);
}

// ---------------- V transpose: VT[bkv][d][s] ----------------
__global__ void v_transpose(const bf16* __restrict__ QKV, bf16* __restrict__ VT) {
  __shared__ bf16 tile[64][66];
  const int bkv = blockIdx.y;
  const int b = bkv >> 2, kv = bkv & 3;
  const int st = blockIdx.x & 31, dt = blockIdx.x >> 5;
  const int s0 = st * 64, d0 = dt * 64;
  const int tj = threadIdx.x & 63, ti = threadIdx.x >> 6;
  for (int i = ti; i < 64; i += 4)
    tile[i][tj] = QKV[(size_t)(b * SEQ + s0 + i) * NQKV + 3072 + kv * HEAD_DIM + d0 + tj];
  __syncthreads();
  for (int i = ti; i < 64; i += 4)
    VT[((size_t)bkv * HEAD_DIM + d0 + i) * SEQ + s0 + tj] = tile[tj][i];
}

// ---------------- flash attention: chunked KV, swapped QK^T, LDS-staged K/V ----
__global__ __launch_bounds__(256) void flash_attn(const bf16* __restrict__ Q,
                                                  const bf16* __restrict__ Kp,
                                                  const bf16* __restrict__ VT,
                                                  bf16* __restrict__ Opart,
                                                  float* __restrict__ ML) {
  __shared__ bf16 Ks[64 * 256];   // [krow][d], 16B chunks XOR-swizzled by (krow&7)
  __shared__ bf16 Vs[256 * 64];   // [d][kv], 16B chunks XOR-swizzled by (d&7)
  __shared__ bf16 pbuf[4][16][80];

  const int tid = threadIdx.x, lane = tid & 63, w = tid >> 6;
  const int l15 = lane & 15, lg = lane >> 4;

  const int cid = blockIdx.x;
  const int bh = cid / CHUNKS_PER_BH;
  const int c  = cid - bh * CHUNKS_PER_BH;
  int qt, ki;
  if (c < 8)       { qt = c;                 ki = 0; }
  else if (c < 24) { qt = 8  + ((c - 8) >> 1);  ki = (c - 8)  & 1; }
  else if (c < 48) { qt = 16 + (c - 24) / 3;    ki = (c - 24) % 3; }
  else             { qt = 24 + ((c - 48) >> 2); ki = (c - 48) & 3; }
  const int kb0 = ki * 8;
  const int kb1 = min(kb0 + 8, qt + 1);

  const int b = bh >> 3, h = bh & 7, kvh = h >> 1;
  const int bkv = b * NKV + kvh;
  const int q0 = qt * 64 + w * 16;

  const bf16* Qb = Q + ((size_t)bh * SEQ + q0) * HEAD_DIM;
  bf16x8 qf[8];
  #pragma unroll
  for (int dc = 0; dc < 8; ++dc)
    qf[dc] = *(const bf16x8*)&Qb[l15 * HEAD_DIM + dc * 32 + lg * 8];

  f32x4 oacc[16] = {};
  float m = -1e30f, l = 0.f;

  const bf16* Ksrc = Kp + (size_t)bkv * SEQ * HEAD_DIM;
  const bf16* Vsrc = VT + (size_t)bkv * HEAD_DIM * SEQ;

  for (int kb = kb0; kb < kb1; ++kb) {
    const int kbase = kb * 64;
    __syncthreads();
    #pragma unroll
    for (int i = 0; i < 8; ++i) {
      int id = i * 256 + tid;
      int row = id >> 5, ch = id & 31;
      int sc = ch ^ (row & 7);
      __builtin_amdgcn_global_load_lds(
          (const __attribute__((address_space(1))) void*)(Ksrc + (size_t)(kbase + row) * HEAD_DIM + sc * 8),
          (__attribute__((address_space(3))) void*)(Ks + id * 8), 16, 0, 0);
    }
    #pragma unroll
    for (int i = 0; i < 8; ++i) {
      int id = i * 256 + tid;
      int row = id >> 3, ch = id & 7;
      int sc = ch ^ (row & 7);
      __builtin_amdgcn_global_load_lds(
          (const __attribute__((address_space(1))) void*)(Vsrc + (size_t)row * SEQ + kbase + sc * 8),
          (__attribute__((address_space(3))) void*)(Vs + id * 8), 16, 0, 0);
    }
    __syncthreads();

    f32x4 sacc[4] = {};
    #pragma unroll
    for (int j = 0; j < 4; ++j) {
      const bf16* kl = &Ks[(j * 16 + l15) * HEAD_DIM];
      #pragma unroll
      for (int dc = 0; dc < 8; ++dc) {
        int ch = (dc * 4 + lg) ^ (l15 & 7);
        bf16x8 kf = *(const bf16x8*)&kl[ch * 8];
        sacc[j] = mfma16(kf, qf[dc], sacc[j]);
      }
    }

    float px[4][4];
    const bool need_mask = (kbase + 63 > q0);
    #pragma unroll
    for (int j = 0; j < 4; ++j)
      #pragma unroll
      for (int r = 0; r < 4; ++r) {
        float v = sacc[j][r] * 0.0625f;
        if (need_mask) {
          int kcol = kbase + j * 16 + lg * 4 + r;
          v = (kcol <= q0 + l15) ? v : -1e30f;
        }
        px[j][r] = v;
      }

    float mx = px[0][0];
    #pragma unroll
    for (int j = 0; j < 4; ++j)
      #pragma unroll
      for (int r = 0; r < 4; ++r) mx = fmaxf(mx, px[j][r]);
    mx = fmaxf(mx, __shfl_xor(mx, 16));
    mx = fmaxf(mx, __shfl_xor(mx, 32));
    float mnew = fmaxf(m, mx);
    float alpha = __expf(m - mnew);
    m = mnew;
    float s = 0.f;
    #pragma unroll
    for (int j = 0; j < 4; ++j) {
      bf16x4 pk;
      #pragma unroll
      for (int r = 0; r < 4; ++r) {
        float e = __expf(px[j][r] - mnew);
        s += e;
        pk[r] = (bf16)e;
      }
      *(bf16x4*)&pbuf[w][l15][j * 16 + lg * 4] = pk;
    }
    s += __shfl_xor(s, 16);
    s += __shfl_xor(s, 32);
    l = l * alpha + s;

    float ar[4];
    #pragma unroll
    for (int r = 0; r < 4; ++r) ar[r] = __shfl(alpha, lg * 4 + r);
    #pragma unroll
    for (int ni = 0; ni < 16; ++ni)
      #pragma unroll
      for (int r = 0; r < 4; ++r) oacc[ni][r] *= ar[r];

    bf16x8 pa0 = *(const bf16x8*)&pbuf[w][l15][lg * 8];
    bf16x8 pa1 = *(const bf16x8*)&pbuf[w][l15][32 + lg * 8];
    #pragma unroll
    for (int ni = 0; ni < 16; ++ni) {
      const bf16* vb = &Vs[(ni * 16 + l15) * 64];
      int c0 = lg ^ (l15 & 7);
      int c1 = (4 + lg) ^ (l15 & 7);
      bf16x8 v0 = *(const bf16x8*)&vb[c0 * 8];
      bf16x8 v1 = *(const bf16x8*)&vb[c1 * 8];
      oacc[ni] = mfma16(pa0, v0, oacc[ni]);
      oacc[ni] = mfma16(pa1, v1, oacc[ni]);
    }
  }

  bf16* Ob = Opart + ((size_t)cid * 64 + w * 16) * HEAD_DIM;
  #pragma unroll
  for (int ni = 0; ni < 16; ++ni)
    #pragma unroll
    for (int r = 0; r < 4; ++r)
      Ob[(size_t)(lg * 4 + r) * HEAD_DIM + ni * 16 + l15] = (bf16)oacc[ni][r];
  if (lg == 0) {
    ML[((size_t)cid * 64 + w * 16 + l15) * 2]     = m;
    ML[((size_t)cid * 64 + w * 16 + l15) * 2 + 1] = l;
  }
}

// ---------------- merge partials -> ao (b, s, h*256+d) bf16 ----------------
__global__ __launch_bounds__(256) void flash_merge(const bf16* __restrict__ Opart,
                                                   const float* __restrict__ ML,
                                                   bf16* __restrict__ AO) {
  const int bh = blockIdx.x, qt = blockIdx.y;
  const int b = bh >> 3, h = bh & 7;
  int cbase, nc;
  if (qt < 8)       { cbase = qt;                nc = 1; }
  else if (qt < 16) { cbase = 8  + 2 * (qt - 8);  nc = 2; }
  else if (qt < 24) { cbase = 24 + 3 * (qt - 16); nc = 3; }
  else              { cbase = 48 + 4 * (qt - 24); nc = 4; }
  const int cid0 = bh * CHUNKS_PER_BH + cbase;

  const int tid = threadIdx.x;
  const int row = tid >> 2, dseg = (tid & 3) * 64;

  float mi[4], li[4];
  float M = -1e30f;
  for (int i = 0; i < nc; ++i) {
    mi[i] = ML[((size_t)(cid0 + i) * 64 + row) * 2];
    li[i] = ML[((size_t)(cid0 + i) * 64 + row) * 2 + 1];
    M = fmaxf(M, mi[i]);
  }
  float wgt[4], L = 0.f;
  for (int i = 0; i < nc; ++i) {
    wgt[i] = __expf(mi[i] - M);
    L += li[i] * wgt[i];
  }
  const float inv = 1.0f / L;

  bf16* dst = AO + ((size_t)(b * SEQ + qt * 64 + row)) * 2048 + h * HEAD_DIM + dseg;
  for (int dv = 0; dv < 8; ++dv) {
    float acc[8] = {};
    for (int i = 0; i < nc; ++i) {
      bf16x8 o = *(const bf16x8*)&Opart[((size_t)(cid0 + i) * 64 + row) * HEAD_DIM + dseg + dv * 8];
      #pragma unroll
      for (int e = 0; e < 8; ++e) acc[e] += wgt[i] * (float)o[e];
    }
    bf16x8 ov;
    #pragma unroll
    for (int e = 0; e < 8; ++e) ov[e] = (bf16)(acc[e] * inv);
    *(bf16x8*)&dst[dv * 8] = ov;
  }
}

// ---------------- launch ----------------
extern "C" void kernel_launch(void* const* d_in, const int* in_sizes, int n_in,
                              void* d_out, int out_size, void* d_ws, size_t ws_size,
                              hipStream_t stream) {
  const float* hs = (const float*)d_in[0];
  const float* Wq = (const float*)d_in[3];
  const float* Wk = (const float*)d_in[4];
  const float* Wv = (const float*)d_in[5];
  const float* Wo = (const float*)d_in[6];
  float* out = (float*)d_out;

  char* ws = (char*)d_ws;
  bf16* hsb  = (bf16*)(ws);                    // 4096x5120        (41,943,040 B)
  bf16* wqkv = (bf16*)(ws + 41943040);         // 4096x5120        (41,943,040 B)
  bf16* qkv  = (bf16*)(ws + 83886080);         // 4096x4096        (33,554,432 B)
  bf16* qr   = (bf16*)(ws + 117440512);        // 2x8x2048x256     (16,777,216 B)
  bf16* kr   = (bf16*)(ws + 134217728);        // 2x4x2048x256     ( 8,388,608 B)
  bf16* vt   = (bf16*)(ws + 142606336);        // 2x4x256x2048     ( 8,388,608 B)
  bf16* ao   = (bf16*)(ws + 150994944);        // 4096x2048        (16,777,216 B)
  bf16* wob  = (bf16*)(ws + 167772160);        // 2560x2048        (10,485,760 B)
  bf16*  opart = (bf16*)(ws);                  // overlay (dead after gemm1)
  float* ml    = (float*)(ws + 41943040);

  hipFuncSetAttribute((const void*)&gemm_pipe<bf16>,  hipFuncAttributeMaxDynamicSharedMemorySize, 131072);
  hipFuncSetAttribute((const void*)&gemm_pipe<float>, hipFuncAttributeMaxDynamicSharedMemorySize, 131072);

  cast8<<<ROWS * IND / 2048, 256, 0, stream>>>(hs, hsb, ROWS * IND);
  cast8<<<2048 * IND / 2048, 256, 0, stream>>>(Wq, wqkv, 2048 * IND);
  cast8<<<1024 * IND / 2048, 256, 0, stream>>>(Wk, wqkv + 2048 * IND, 1024 * IND);
  cast8<<<1024 * IND / 2048, 256, 0, stream>>>(Wv, wqkv + 3072 * IND, 1024 * IND);
  cast8<<<HID * 2048 / 2048, 256, 0, stream>>>(Wo, wob, HID * 2048);

  // QKV projection: (4096x5120) @ (4096x5120)^T -> 4096x4096, grid 16x16=256 wg
  gemm_pipe<bf16><<<dim3(NQKV / 256, ROWS / 256), 512, 131072, stream>>>(hsb, wqkv, qkv, ROWS, NQKV, IND);

  rope_reorder<<<dim3(ROWS, 12), 128, 0, stream>>>(qkv, qr, kr);
  v_transpose<<<dim3(128, BATCH * NKV), 256, 0, stream>>>(qkv, vt);

  flash_attn<<<dim3(16 * CHUNKS_PER_BH), 256, 0, stream>>>(qr, kr, vt, opart, ml);
  flash_merge<<<dim3(16, 32), 256, 0, stream>>>(opart, ml, ao);

  // output projection: (4096x2048) @ (2560x2048)^T -> 4096x2560 fp32, grid 10x16=160 wg
  gemm_pipe<float><<<dim3(HID / 256, ROWS / 256), 512, 131072, stream>>>(ao, wob, out, ROWS, HID, 2048);
}

// Round 4
// 415.706 us; speedup vs baseline: 1.8286x; 1.0678x over previous
//
#include <hip/hip_runtime.h>
#include <hip/hip_bf16.h>
#include <cstdint>
#include <cstddef>

typedef __bf16 bf16;
typedef bf16 bf16x4 __attribute__((ext_vector_type(4)));
typedef bf16 bf16x8 __attribute__((ext_vector_type(8)));
typedef float f32x4 __attribute__((ext_vector_type(4)));

#define HEAD_DIM 256
#define NHEADS 8
#define NKV 4
#define BATCH 2
#define SEQ 2048
#define IND 5120
#define HID 2560
#define ROWS (BATCH*SEQ)   // 4096
#define NQKV 4096          // 2048 + 1024 + 1024
#define CHUNKS_PER_BH 80   // sum over qt of ceil((qt+1)/8)

__device__ __forceinline__ f32x4 mfma16(bf16x8 a, bf16x8 b, f32x4 c) {
  return __builtin_amdgcn_mfma_f32_16x16x32_bf16(a, b, c, 0, 0, 0);
}

// ---------------- fused cast fp32 -> bf16 for all 5 tensors ----------------
// segments (element offsets): hs[0,20971520) Wq[..31457280) Wk[..36700160)
// Wv[..41943040) -> dst01 linear;  Wo[..47185920) -> dwo.
__global__ void cast_all(const float* __restrict__ hs, const float* __restrict__ wq,
                         const float* __restrict__ wk, const float* __restrict__ wv,
                         const float* __restrict__ wo,
                         bf16* __restrict__ dst01, bf16* __restrict__ dwo) {
  long i = ((long)blockIdx.x * 256 + threadIdx.x) * 8;
  const float* src; bf16* dst;
  if (i < 20971520L)      { src = hs + i;              dst = dst01 + i; }
  else if (i < 31457280L) { src = wq + (i - 20971520); dst = dst01 + i; }
  else if (i < 36700160L) { src = wk + (i - 31457280); dst = dst01 + i; }
  else if (i < 41943040L) { src = wv + (i - 36700160); dst = dst01 + i; }
  else                    { src = wo + (i - 41943040); dst = dwo + (i - 41943040); }
  float4 a = *(const float4*)(src);
  float4 b = *(const float4*)(src + 4);
  bf16x8 o;
  o[0] = (bf16)a.x; o[1] = (bf16)a.y; o[2] = (bf16)a.z; o[3] = (bf16)a.w;
  o[4] = (bf16)b.x; o[5] = (bf16)b.y; o[6] = (bf16)b.z; o[7] = (bf16)b.w;
  *(bf16x8*)dst = o;
}

// ---------------- pipelined BT GEMM: C[m,n] = sum_k A[m,k]*B[n,k] ----------------
// 256x256 tile, BK=32, 512 thr / 8 waves (2Mx4N), per-wave 128x64 out (acc[8][4]).
// 4-slot LDS ring (128 KiB), 3 K-tiles prefetched, counted vmcnt (never 0),
// raw s_barrier + sched_barrier(0) fences, XOR-swizzled chunks.
// READS-ONE-ITER-AHEAD: iter t issues ds_reads of tile t+1 into the alternate
// register set, then MFMAs tile t from registers read last iter -> LDS reads
// overlap the MFMA cluster instead of stalling it.
// Ledger: vmcnt(4) at iter top => tile t+1 DMA landed (outstanding = t+1,t+2);
// barrier separates all waves' tile-(t-1) read completion (enforced by their
// iter-(t-1) MFMA lgkm waits) from iter-t stage into that slot.
template<typename OutT>
__global__ __launch_bounds__(512, 2) void gemm_pipe(const bf16* __restrict__ A,
                                                    const bf16* __restrict__ B,
                                                    OutT* __restrict__ C,
                                                    int M, int N, int K) {
  extern __shared__ bf16 smem[];  // 4 slots x (8192 A + 8192 B) bf16 = 128 KiB
  const int tid = threadIdx.x;
  const int lane = tid & 63, w = tid >> 6;
  const int wm = w >> 2, wn = w & 3;
  const int l15 = lane & 15, lg = lane >> 4;
  const int gx = gridDim.x;
  const int nwg = gx * gridDim.y;
  const int id = blockIdx.y * gx + blockIdx.x;
  const int nid = (id & 7) * (nwg >> 3) + (id >> 3);   // bijective: nwg % 8 == 0
  const int m0 = (nid / gx) * 256, n0 = (nid % gx) * 256;
  const int NT = K >> 5;   // assumed even, >= 4

  auto stage = [&](int slot, int kt) {
    bf16* sl = smem + slot * 16384;
    #pragma unroll
    for (int i = 0; i < 2; ++i) {
      int cid = i * 512 + tid;
      int row = cid >> 2;
      int sch = (cid & 3) ^ (row & 3);
      __builtin_amdgcn_global_load_lds(
        (const __attribute__((address_space(1))) void*)(A + (size_t)(m0 + row) * K + kt * 32 + sch * 8),
        (__attribute__((address_space(3))) void*)(sl + cid * 8), 16, 0, 0);
    }
    #pragma unroll
    for (int i = 0; i < 2; ++i) {
      int cid = i * 512 + tid;
      int row = cid >> 2;
      int sch = (cid & 3) ^ (row & 3);
      __builtin_amdgcn_global_load_lds(
        (const __attribute__((address_space(1))) void*)(B + (size_t)(n0 + row) * K + kt * 32 + sch * 8),
        (__attribute__((address_space(3))) void*)(sl + 8192 + cid * 8), 16, 0, 0);
    }
  };

  // fragment LDS element offsets (row&3 == l15&3 since mi*16, wm*128 are mult of 4)
  const int ach = lg ^ (l15 & 3);
  const int aoff = ((wm * 128 + l15) * 4 + ach) * 8;
  const int boff = 8192 + ((wn * 64 + l15) * 4 + ach) * 8;

  auto read_slot = [&](const bf16* sl, bf16x8 (&a)[8], bf16x8 (&b)[4]) {
    #pragma unroll
    for (int mi = 0; mi < 8; ++mi) a[mi] = *(const bf16x8*)&sl[aoff + mi * 512];
    #pragma unroll
    for (int ni = 0; ni < 4; ++ni) b[ni] = *(const bf16x8*)&sl[boff + ni * 512];
  };

  f32x4 acc[8][4] = {};
  auto domfma = [&](bf16x8 (&a)[8], bf16x8 (&b)[4]) {
    __builtin_amdgcn_s_setprio(1);
    #pragma unroll
    for (int ni = 0; ni < 4; ++ni)
      #pragma unroll
      for (int mi = 0; mi < 8; ++mi)
        acc[mi][ni] = mfma16(a[mi], b[ni], acc[mi][ni]);
    __builtin_amdgcn_s_setprio(0);
  };

  bf16x8 aE[8], bE[4], aO[8], bO[4];
  stage(0, 0); stage(1, 1); stage(2, 2);   // 12 loads in flight
  asm volatile("s_waitcnt vmcnt(8)" ::: "memory");   // tile 0 landed
  __builtin_amdgcn_s_barrier();
  __builtin_amdgcn_sched_barrier(0);
  read_slot(smem, aE, bE);

  int t = 0;
  for (; t < NT - 2; t += 2) {
    // even iter: consume E(tile t), read O(tile t+1), stage t+3
    asm volatile("s_waitcnt vmcnt(4)" ::: "memory");
    __builtin_amdgcn_s_barrier();
    __builtin_amdgcn_sched_barrier(0);
    read_slot(smem + ((t + 1) & 3) * 16384, aO, bO);
    { int kt = t + 3; if (kt > NT - 1) kt = NT - 1; stage((t + 3) & 3, kt); }
    domfma(aE, bE);
    // odd iter: consume O(tile t+1), read E(tile t+2), stage t+4
    asm volatile("s_waitcnt vmcnt(4)" ::: "memory");
    __builtin_amdgcn_s_barrier();
    __builtin_amdgcn_sched_barrier(0);
    read_slot(smem + ((t + 2) & 3) * 16384, aE, bE);
    { int kt = t + 4; if (kt > NT - 1) kt = NT - 1; stage((t + 4) & 3, kt); }
    domfma(aO, bO);
  }
  // tail: t == NT-2
  asm volatile("s_waitcnt vmcnt(4)" ::: "memory");
  __builtin_amdgcn_s_barrier();
  __builtin_amdgcn_sched_barrier(0);
  read_slot(smem + ((NT - 1) & 3) * 16384, aO, bO);
  domfma(aE, bE);
  domfma(aO, bO);

  #pragma unroll
  for (int mi = 0; mi < 8; ++mi)
    #pragma unroll
    for (int ni = 0; ni < 4; ++ni) {
      int row = m0 + wm * 128 + mi * 16 + lg * 4;
      int col = n0 + wn * 64 + ni * 16 + l15;
      #pragma unroll
      for (int r = 0; r < 4; ++r)
        C[(size_t)(row + r) * N + col] = (OutT)acc[mi][ni][r];
    }
}

// ---------------- RoPE + reorder into Q (B,H,S,D) and K (B,KV,S,D) ----------------
__global__ void rope_reorder(const bf16* __restrict__ QKV,
                             bf16* __restrict__ Qr, bf16* __restrict__ Kr) {
  const int row = blockIdx.x;   // b*SEQ + s
  const int slot = blockIdx.y;  // 0..7 q heads, 8..11 k heads
  const int d = threadIdx.x;    // 0..127
  const int b = row >> 11, s = row & 2047;
  const bool isq = slot < 8;
  const int col0 = isq ? slot * HEAD_DIM : 2048 + (slot - 8) * HEAD_DIM;
  float x1 = (float)QKV[(size_t)row * NQKV + col0 + d];
  float x2 = (float)QKV[(size_t)row * NQKV + col0 + d + 128];
  float invf = exp2f((float)d * (-13.287712379549449f / 128.0f)); // 10000^(-d/128)
  float fr = (float)s * invf;
  float sn, cs;
  sincosf(fr, &sn, &cs);
  bf16* dst = isq ? (Qr + ((size_t)(b * NHEADS + slot) * SEQ + s) * HEAD_DIM)
                  : (Kr + ((size_t)(b * NKV + (slot - 8)) * SEQ + s) * HEAD_DIM);
  dst[d]       = (bf16)(x1 * cs - x2 * sn);
  dst[d + 128] = (bf16)(x2 * cs + x1 * sn);
}

// ---------------- V transpose: VT[bkv][d][s] ----------------
__global__ void v_transpose(const bf16* __restrict__ QKV, bf16* __restrict__ VT) {
  __shared__ bf16 tile[64][66];
  const int bkv = blockIdx.y;
  const int b = bkv >> 2, kv = bkv & 3;
  const int st = blockIdx.x & 31, dt = blockIdx.x >> 5;
  const int s0 = st * 64, d0 = dt * 64;
  const int tj = threadIdx.x & 63, ti = threadIdx.x >> 6;
  for (int i = ti; i < 64; i += 4)
    tile[i][tj] = QKV[(size_t)(b * SEQ + s0 + i) * NQKV + 3072 + kv * HEAD_DIM + d0 + tj];
  __syncthreads();
  for (int i = ti; i < 64; i += 4)
    VT[((size_t)bkv * HEAD_DIM + d0 + i) * SEQ + s0 + tj] = tile[tj][i];
}

// ---------------- flash attention: chunked KV, swapped QK^T, LDS-staged K/V ----
__global__ __launch_bounds__(256) void flash_attn(const bf16* __restrict__ Q,
                                                  const bf16* __restrict__ Kp,
                                                  const bf16* __restrict__ VT,
                                                  bf16* __restrict__ Opart,
                                                  float* __restrict__ ML) {
  __shared__ bf16 Ks[64 * 256];   // [krow][d], 16B chunks XOR-swizzled by (krow&7)
  __shared__ bf16 Vs[256 * 64];   // [d][kv], 16B chunks XOR-swizzled by (d&7)
  __shared__ bf16 pbuf[4][16][80];

  const int tid = threadIdx.x, lane = tid & 63, w = tid >> 6;
  const int l15 = lane & 15, lg = lane >> 4;

  const int cid = blockIdx.x;
  const int bh = cid / CHUNKS_PER_BH;
  const int c  = cid - bh * CHUNKS_PER_BH;
  int qt, ki;
  if (c < 8)       { qt = c;                 ki = 0; }
  else if (c < 24) { qt = 8  + ((c - 8) >> 1);  ki = (c - 8)  & 1; }
  else if (c < 48) { qt = 16 + (c - 24) / 3;    ki = (c - 24) % 3; }
  else             { qt = 24 + ((c - 48) >> 2); ki = (c - 48) & 3; }
  const int kb0 = ki * 8;
  const int kb1 = min(kb0 + 8, qt + 1);

  const int b = bh >> 3, h = bh & 7, kvh = h >> 1;
  const int bkv = b * NKV + kvh;
  const int q0 = qt * 64 + w * 16;

  const bf16* Qb = Q + ((size_t)bh * SEQ + q0) * HEAD_DIM;
  bf16x8 qf[8];
  #pragma unroll
  for (int dc = 0; dc < 8; ++dc)
    qf[dc] = *(const bf16x8*)&Qb[l15 * HEAD_DIM + dc * 32 + lg * 8];

  f32x4 oacc[16] = {};
  float m = -1e30f, l = 0.f;

  const bf16* Ksrc = Kp + (size_t)bkv * SEQ * HEAD_DIM;
  const bf16* Vsrc = VT + (size_t)bkv * HEAD_DIM * SEQ;

  for (int kb = kb0; kb < kb1; ++kb) {
    const int kbase = kb * 64;
    __syncthreads();
    #pragma unroll
    for (int i = 0; i < 8; ++i) {
      int id = i * 256 + tid;
      int row = id >> 5, ch = id & 31;
      int sc = ch ^ (row & 7);
      __builtin_amdgcn_global_load_lds(
          (const __attribute__((address_space(1))) void*)(Ksrc + (size_t)(kbase + row) * HEAD_DIM + sc * 8),
          (__attribute__((address_space(3))) void*)(Ks + id * 8), 16, 0, 0);
    }
    #pragma unroll
    for (int i = 0; i < 8; ++i) {
      int id = i * 256 + tid;
      int row = id >> 3, ch = id & 7;
      int sc = ch ^ (row & 7);
      __builtin_amdgcn_global_load_lds(
          (const __attribute__((address_space(1))) void*)(Vsrc + (size_t)row * SEQ + kbase + sc * 8),
          (__attribute__((address_space(3))) void*)(Vs + id * 8), 16, 0, 0);
    }
    __syncthreads();

    f32x4 sacc[4] = {};
    #pragma unroll
    for (int j = 0; j < 4; ++j) {
      const bf16* kl = &Ks[(j * 16 + l15) * HEAD_DIM];
      #pragma unroll
      for (int dc = 0; dc < 8; ++dc) {
        int ch = (dc * 4 + lg) ^ (l15 & 7);
        bf16x8 kf = *(const bf16x8*)&kl[ch * 8];
        sacc[j] = mfma16(kf, qf[dc], sacc[j]);
      }
    }

    float px[4][4];
    const bool need_mask = (kbase + 63 > q0);
    #pragma unroll
    for (int j = 0; j < 4; ++j)
      #pragma unroll
      for (int r = 0; r < 4; ++r) {
        float v = sacc[j][r] * 0.0625f;
        if (need_mask) {
          int kcol = kbase + j * 16 + lg * 4 + r;
          v = (kcol <= q0 + l15) ? v : -1e30f;
        }
        px[j][r] = v;
      }

    float mx = px[0][0];
    #pragma unroll
    for (int j = 0; j < 4; ++j)
      #pragma unroll
      for (int r = 0; r < 4; ++r) mx = fmaxf(mx, px[j][r]);
    mx = fmaxf(mx, __shfl_xor(mx, 16));
    mx = fmaxf(mx, __shfl_xor(mx, 32));
    float mnew = fmaxf(m, mx);
    float alpha = __expf(m - mnew);
    m = mnew;
    float s = 0.f;
    #pragma unroll
    for (int j = 0; j < 4; ++j) {
      bf16x4 pk;
      #pragma unroll
      for (int r = 0; r < 4; ++r) {
        float e = __expf(px[j][r] - mnew);
        s += e;
        pk[r] = (bf16)e;
      }
      *(bf16x4*)&pbuf[w][l15][j * 16 + lg * 4] = pk;
    }
    s += __shfl_xor(s, 16);
    s += __shfl_xor(s, 32);
    l = l * alpha + s;

    float ar[4];
    #pragma unroll
    for (int r = 0; r < 4; ++r) ar[r] = __shfl(alpha, lg * 4 + r);
    #pragma unroll
    for (int ni = 0; ni < 16; ++ni)
      #pragma unroll
      for (int r = 0; r < 4; ++r) oacc[ni][r] *= ar[r];

    bf16x8 pa0 = *(const bf16x8*)&pbuf[w][l15][lg * 8];
    bf16x8 pa1 = *(const bf16x8*)&pbuf[w][l15][32 + lg * 8];
    #pragma unroll
    for (int ni = 0; ni < 16; ++ni) {
      const bf16* vb = &Vs[(ni * 16 + l15) * 64];
      int c0 = lg ^ (l15 & 7);
      int c1 = (4 + lg) ^ (l15 & 7);
      bf16x8 v0 = *(const bf16x8*)&vb[c0 * 8];
      bf16x8 v1 = *(const bf16x8*)&vb[c1 * 8];
      oacc[ni] = mfma16(pa0, v0, oacc[ni]);
      oacc[ni] = mfma16(pa1, v1, oacc[ni]);
    }
  }

  bf16* Ob = Opart + ((size_t)cid * 64 + w * 16) * HEAD_DIM;
  #pragma unroll
  for (int ni = 0; ni < 16; ++ni)
    #pragma unroll
    for (int r = 0; r < 4; ++r)
      Ob[(size_t)(lg * 4 + r) * HEAD_DIM + ni * 16 + l15] = (bf16)oacc[ni][r];
  if (lg == 0) {
    ML[((size_t)cid * 64 + w * 16 + l15) * 2]     = m;
    ML[((size_t)cid * 64 + w * 16 + l15) * 2 + 1] = l;
  }
}

// ---------------- merge partials -> ao (b, s, h*256+d) bf16 ----------------
__global__ __launch_bounds__(256) void flash_merge(const bf16* __restrict__ Opart,
                                                   const float* __restrict__ ML,
                                                   bf16* __restrict__ AO) {
  const int bh = blockIdx.x, qt = blockIdx.y;
  const int b = bh >> 3, h = bh & 7;
  int cbase, nc;
  if (qt < 8)       { cbase = qt;                nc = 1; }
  else if (qt < 16) { cbase = 8  + 2 * (qt - 8);  nc = 2; }
  else if (qt < 24) { cbase = 24 + 3 * (qt - 16); nc = 3; }
  else              { cbase = 48 + 4 * (qt - 24); nc = 4; }
  const int cid0 = bh * CHUNKS_PER_BH + cbase;

  const int tid = threadIdx.x;
  const int row = tid >> 2, dseg = (tid & 3) * 64;

  float mi[4], li[4];
  float M = -1e30f;
  for (int i = 0; i < nc; ++i) {
    mi[i] = ML[((size_t)(cid0 + i) * 64 + row) * 2];
    li[i] = ML[((size_t)(cid0 + i) * 64 + row) * 2 + 1];
    M = fmaxf(M, mi[i]);
  }
  float wgt[4], L = 0.f;
  for (int i = 0; i < nc; ++i) {
    wgt[i] = __expf(mi[i] - M);
    L += li[i] * wgt[i];
  }
  const float inv = 1.0f / L;

  bf16* dst = AO + ((size_t)(b * SEQ + qt * 64 + row)) * 2048 + h * HEAD_DIM + dseg;
  for (int dv = 0; dv < 8; ++dv) {
    float acc[8] = {};
    for (int i = 0; i < nc; ++i) {
      bf16x8 o = *(const bf16x8*)&Opart[((size_t)(cid0 + i) * 64 + row) * HEAD_DIM + dseg + dv * 8];
      #pragma unroll
      for (int e = 0; e < 8; ++e) acc[e] += wgt[i] * (float)o[e];
    }
    bf16x8 ov;
    #pragma unroll
    for (int e = 0; e < 8; ++e) ov[e] = (bf16)(acc[e] * inv);
    *(bf16x8*)&dst[dv * 8] = ov;
  }
}

// ---------------- launch ----------------
extern "C" void kernel_launch(void* const* d_in, const int* in_sizes, int n_in,
                              void* d_out, int out_size, void* d_ws, size_t ws_size,
                              hipStream_t stream) {
  const float* hs = (const float*)d_in[0];
  const float* Wq = (const float*)d_in[3];
  const float* Wk = (const float*)d_in[4];
  const float* Wv = (const float*)d_in[5];
  const float* Wo = (const float*)d_in[6];
  float* out = (float*)d_out;

  char* ws = (char*)d_ws;
  bf16* hsb  = (bf16*)(ws);                    // 4096x5120        (41,943,040 B)
  bf16* wqkv = (bf16*)(ws + 41943040);         // 4096x5120        (41,943,040 B)
  bf16* qkv  = (bf16*)(ws + 83886080);         // 4096x4096        (33,554,432 B)
  bf16* qr   = (bf16*)(ws + 117440512);        // 2x8x2048x256     (16,777,216 B)
  bf16* kr   = (bf16*)(ws + 134217728);        // 2x4x2048x256     ( 8,388,608 B)
  bf16* vt   = (bf16*)(ws + 142606336);        // 2x4x256x2048     ( 8,388,608 B)
  bf16* ao   = (bf16*)(ws + 150994944);        // 4096x2048        (16,777,216 B)
  bf16* wob  = (bf16*)(ws + 167772160);        // 2560x2048        (10,485,760 B)
  bf16*  opart = (bf16*)(ws);                  // overlay (dead after gemm1)
  float* ml    = (float*)(ws + 41943040);

  hipFuncSetAttribute((const void*)&gemm_pipe<bf16>,  hipFuncAttributeMaxDynamicSharedMemorySize, 131072);
  hipFuncSetAttribute((const void*)&gemm_pipe<float>, hipFuncAttributeMaxDynamicSharedMemorySize, 131072);

  // fused casts: 47,185,920 elems / 2048 per block = 23040 blocks
  cast_all<<<23040, 256, 0, stream>>>(hs, Wq, Wk, Wv, Wo, (bf16*)ws, wob);

  // QKV projection: (4096x5120) @ (4096x5120)^T -> 4096x4096, grid 16x16=256 wg
  gemm_pipe<bf16><<<dim3(NQKV / 256, ROWS / 256), 512, 131072, stream>>>(hsb, wqkv, qkv, ROWS, NQKV, IND);

  rope_reorder<<<dim3(ROWS, 12), 128, 0, stream>>>(qkv, qr, kr);
  v_transpose<<<dim3(128, BATCH * NKV), 256, 0, stream>>>(qkv, vt);

  flash_attn<<<dim3(16 * CHUNKS_PER_BH), 256, 0, stream>>>(qr, kr, vt, opart, ml);
  flash_merge<<<dim3(16, 32), 256, 0, stream>>>(opart, ml, ao);

  // output projection: (4096x2048) @ (2560x2048)^T -> 4096x2560 fp32, grid 10x16=160 wg
  gemm_pipe<float><<<dim3(HID / 256, ROWS / 256), 512, 131072, stream>>>(ao, wob, out, ROWS, HID, 2048);
}

// Round 5
// 410.147 us; speedup vs baseline: 1.8534x; 1.0136x over previous
//
#include <hip/hip_runtime.h>
#include <hip/hip_bf16.h>
#include <cstdint>
#include <cstddef>

typedef __bf16 bf16;
typedef bf16 bf16x4 __attribute__((ext_vector_type(4)));
typedef bf16 bf16x8 __attribute__((ext_vector_type(8)));
typedef float f32x4 __attribute__((ext_vector_type(4)));

#define HEAD_DIM 256
#define NHEADS 8
#define NKV 4
#define BATCH 2
#define SEQ 2048
#define IND 5120
#define HID 2560
#define ROWS (BATCH*SEQ)   // 4096
#define NQKV 4096          // 2048 + 1024 + 1024
#define CHUNKS_PER_BH 80   // sum over qt of ceil((qt+1)/8)

__device__ __forceinline__ f32x4 mfma16(bf16x8 a, bf16x8 b, f32x4 c) {
  return __builtin_amdgcn_mfma_f32_16x16x32_bf16(a, b, c, 0, 0, 0);
}

// ---------------- fused cast fp32 -> bf16 for all 5 tensors ----------------
__global__ void cast_all(const float* __restrict__ hs, const float* __restrict__ wq,
                         const float* __restrict__ wk, const float* __restrict__ wv,
                         const float* __restrict__ wo,
                         bf16* __restrict__ dst01, bf16* __restrict__ dwo) {
  long i = ((long)blockIdx.x * 256 + threadIdx.x) * 8;
  const float* src; bf16* dst;
  if (i < 20971520L)      { src = hs + i;              dst = dst01 + i; }
  else if (i < 31457280L) { src = wq + (i - 20971520); dst = dst01 + i; }
  else if (i < 36700160L) { src = wk + (i - 31457280); dst = dst01 + i; }
  else if (i < 41943040L) { src = wv + (i - 36700160); dst = dst01 + i; }
  else                    { src = wo + (i - 41943040); dst = dwo + (i - 41943040); }
  float4 a = *(const float4*)(src);
  float4 b = *(const float4*)(src + 4);
  bf16x8 o;
  o[0] = (bf16)a.x; o[1] = (bf16)a.y; o[2] = (bf16)a.z; o[3] = (bf16)a.w;
  o[4] = (bf16)b.x; o[5] = (bf16)b.y; o[6] = (bf16)b.z; o[7] = (bf16)b.w;
  *(bf16x8*)dst = o;
}

// ---------------- pipelined BT GEMM: C[m,n] = sum_k A[m,k]*B[n,k] ----------------
// 256x256 tile, BK=32, 512 thr / 8 waves (2Mx4N), per-wave 128x64 out (acc[8][4]).
// 4-slot LDS ring (128 KiB), 3 K-tiles prefetched, counted vmcnt (never 0),
// raw s_barrier + sched_barrier(0) fences, reads-one-iter-ahead.
// Chunk swizzle: slot = chunk ^ ((row>>1)&3). Row = 64 B = half a 128-B bank
// line, so bank group = (row&1, slot): for each consecutive-8 lane group
// (fixed lg, l15=0..7) the pair (l15&1, lg^((l15>>1)&3)) covers all 8 distinct
// 16-B slots -> conflict-free ds_read_b128. (Old (row&3) XOR collided l15 and
// l15+4 on the same banks: 2-way conflict, 383 cyc/blk-iter measured.)
template<typename OutT>
__global__ __launch_bounds__(512, 2) void gemm_pipe(const bf16* __restrict__ A,
                                                    const bf16* __restrict__ B,
                                                    OutT* __restrict__ C,
                                                    int M, int N, int K) {
  extern __shared__ bf16 smem[];  // 4 slots x (8192 A + 8192 B) bf16 = 128 KiB
  const int tid = threadIdx.x;
  const int lane = tid & 63, w = tid >> 6;
  const int wm = w >> 2, wn = w & 3;
  const int l15 = lane & 15, lg = lane >> 4;
  const int gx = gridDim.x;
  const int nwg = gx * gridDim.y;
  const int id = blockIdx.y * gx + blockIdx.x;
  const int nid = (id & 7) * (nwg >> 3) + (id >> 3);   // bijective: nwg % 8 == 0
  const int m0 = (nid / gx) * 256, n0 = (nid % gx) * 256;
  const int NT = K >> 5;   // assumed even, >= 4

  auto stage = [&](int slot, int kt) {
    bf16* sl = smem + slot * 16384;
    #pragma unroll
    for (int i = 0; i < 2; ++i) {
      int cid = i * 512 + tid;
      int sch = (cid & 3) ^ ((cid >> 3) & 3);          // chunk ^ ((row>>1)&3)
      __builtin_amdgcn_global_load_lds(
        (const __attribute__((address_space(1))) void*)(A + (size_t)(m0 + (cid >> 2)) * K + kt * 32 + sch * 8),
        (__attribute__((address_space(3))) void*)(sl + cid * 8), 16, 0, 0);
    }
    #pragma unroll
    for (int i = 0; i < 2; ++i) {
      int cid = i * 512 + tid;
      int sch = (cid & 3) ^ ((cid >> 3) & 3);
      __builtin_amdgcn_global_load_lds(
        (const __attribute__((address_space(1))) void*)(B + (size_t)(n0 + (cid >> 2)) * K + kt * 32 + sch * 8),
        (__attribute__((address_space(3))) void*)(sl + 8192 + cid * 8), 16, 0, 0);
    }
  };

  // fragment LDS element offsets; (row>>1)&3 == (l15>>1)&3 since wm*128, mi*16
  // contribute multiples of 8 to row>>1
  const int ach = lg ^ ((l15 >> 1) & 3);
  const int aoff = ((wm * 128 + l15) * 4 + ach) * 8;
  const int boff = 8192 + ((wn * 64 + l15) * 4 + ach) * 8;

  auto read_slot = [&](const bf16* sl, bf16x8 (&a)[8], bf16x8 (&b)[4]) {
    #pragma unroll
    for (int mi = 0; mi < 8; ++mi) a[mi] = *(const bf16x8*)&sl[aoff + mi * 512];
    #pragma unroll
    for (int ni = 0; ni < 4; ++ni) b[ni] = *(const bf16x8*)&sl[boff + ni * 512];
  };

  f32x4 acc[8][4] = {};
  auto domfma = [&](bf16x8 (&a)[8], bf16x8 (&b)[4]) {
    __builtin_amdgcn_s_setprio(1);
    #pragma unroll
    for (int ni = 0; ni < 4; ++ni)
      #pragma unroll
      for (int mi = 0; mi < 8; ++mi)
        acc[mi][ni] = mfma16(a[mi], b[ni], acc[mi][ni]);
    __builtin_amdgcn_s_setprio(0);
  };

  bf16x8 aE[8], bE[4], aO[8], bO[4];
  stage(0, 0); stage(1, 1); stage(2, 2);   // 12 loads in flight
  asm volatile("s_waitcnt vmcnt(8)" ::: "memory");   // tile 0 landed
  __builtin_amdgcn_s_barrier();
  __builtin_amdgcn_sched_barrier(0);
  read_slot(smem, aE, bE);

  int t = 0;
  for (; t < NT - 2; t += 2) {
    // even iter: consume E(tile t), read O(tile t+1), stage t+3
    asm volatile("s_waitcnt vmcnt(4)" ::: "memory");
    __builtin_amdgcn_s_barrier();
    __builtin_amdgcn_sched_barrier(0);
    read_slot(smem + ((t + 1) & 3) * 16384, aO, bO);
    { int kt = t + 3; if (kt > NT - 1) kt = NT - 1; stage((t + 3) & 3, kt); }
    domfma(aE, bE);
    // odd iter: consume O(tile t+1), read E(tile t+2), stage t+4
    asm volatile("s_waitcnt vmcnt(4)" ::: "memory");
    __builtin_amdgcn_s_barrier();
    __builtin_amdgcn_sched_barrier(0);
    read_slot(smem + ((t + 2) & 3) * 16384, aE, bE);
    { int kt = t + 4; if (kt > NT - 1) kt = NT - 1; stage((t + 4) & 3, kt); }
    domfma(aO, bO);
  }
  // tail: t == NT-2
  asm volatile("s_waitcnt vmcnt(4)" ::: "memory");
  __builtin_amdgcn_s_barrier();
  __builtin_amdgcn_sched_barrier(0);
  read_slot(smem + ((NT - 1) & 3) * 16384, aO, bO);
  domfma(aE, bE);
  domfma(aO, bO);

  #pragma unroll
  for (int mi = 0; mi < 8; ++mi)
    #pragma unroll
    for (int ni = 0; ni < 4; ++ni) {
      int row = m0 + wm * 128 + mi * 16 + lg * 4;
      int col = n0 + wn * 64 + ni * 16 + l15;
      #pragma unroll
      for (int r = 0; r < 4; ++r)
        C[(size_t)(row + r) * N + col] = (OutT)acc[mi][ni][r];
    }
}

// ---------------- RoPE + reorder into Q (B,H,S,D) and K (B,KV,S,D) ----------------
__global__ void rope_reorder(const bf16* __restrict__ QKV,
                             bf16* __restrict__ Qr, bf16* __restrict__ Kr) {
  const int row = blockIdx.x;   // b*SEQ + s
  const int slot = blockIdx.y;  // 0..7 q heads, 8..11 k heads
  const int d = threadIdx.x;    // 0..127
  const int b = row >> 11, s = row & 2047;
  const bool isq = slot < 8;
  const int col0 = isq ? slot * HEAD_DIM : 2048 + (slot - 8) * HEAD_DIM;
  float x1 = (float)QKV[(size_t)row * NQKV + col0 + d];
  float x2 = (float)QKV[(size_t)row * NQKV + col0 + d + 128];
  float invf = exp2f((float)d * (-13.287712379549449f / 128.0f)); // 10000^(-d/128)
  float fr = (float)s * invf;
  float sn, cs;
  sincosf(fr, &sn, &cs);
  bf16* dst = isq ? (Qr + ((size_t)(b * NHEADS + slot) * SEQ + s) * HEAD_DIM)
                  : (Kr + ((size_t)(b * NKV + (slot - 8)) * SEQ + s) * HEAD_DIM);
  dst[d]       = (bf16)(x1 * cs - x2 * sn);
  dst[d + 128] = (bf16)(x2 * cs + x1 * sn);
}

// ---------------- V transpose: VT[bkv][d][s] ----------------
__global__ void v_transpose(const bf16* __restrict__ QKV, bf16* __restrict__ VT) {
  __shared__ bf16 tile[64][66];
  const int bkv = blockIdx.y;
  const int b = bkv >> 2, kv = bkv & 3;
  const int st = blockIdx.x & 31, dt = blockIdx.x >> 5;
  const int s0 = st * 64, d0 = dt * 64;
  const int tj = threadIdx.x & 63, ti = threadIdx.x >> 6;
  for (int i = ti; i < 64; i += 4)
    tile[i][tj] = QKV[(size_t)(b * SEQ + s0 + i) * NQKV + 3072 + kv * HEAD_DIM + d0 + tj];
  __syncthreads();
  for (int i = ti; i < 64; i += 4)
    VT[((size_t)bkv * HEAD_DIM + d0 + i) * SEQ + s0 + tj] = tile[tj][i];
}

// ---------------- flash attention: chunked KV, swapped QK^T, LDS-staged K/V ----
__global__ __launch_bounds__(256) void flash_attn(const bf16* __restrict__ Q,
                                                  const bf16* __restrict__ Kp,
                                                  const bf16* __restrict__ VT,
                                                  bf16* __restrict__ Opart,
                                                  float* __restrict__ ML) {
  __shared__ bf16 Ks[64 * 256];   // [krow][d], 16B chunks XOR-swizzled by (krow&7)
  __shared__ bf16 Vs[256 * 64];   // [d][kv], 16B chunks XOR-swizzled by (d&7)
  __shared__ bf16 pbuf[4][16][80];

  const int tid = threadIdx.x, lane = tid & 63, w = tid >> 6;
  const int l15 = lane & 15, lg = lane >> 4;

  const int cid = blockIdx.x;
  const int bh = cid / CHUNKS_PER_BH;
  const int c  = cid - bh * CHUNKS_PER_BH;
  int qt, ki;
  if (c < 8)       { qt = c;                 ki = 0; }
  else if (c < 24) { qt = 8  + ((c - 8) >> 1);  ki = (c - 8)  & 1; }
  else if (c < 48) { qt = 16 + (c - 24) / 3;    ki = (c - 24) % 3; }
  else             { qt = 24 + ((c - 48) >> 2); ki = (c - 48) & 3; }
  const int kb0 = ki * 8;
  const int kb1 = min(kb0 + 8, qt + 1);

  const int b = bh >> 3, h = bh & 7, kvh = h >> 1;
  const int bkv = b * NKV + kvh;
  const int q0 = qt * 64 + w * 16;

  const bf16* Qb = Q + ((size_t)bh * SEQ + q0) * HEAD_DIM;
  bf16x8 qf[8];
  #pragma unroll
  for (int dc = 0; dc < 8; ++dc)
    qf[dc] = *(const bf16x8*)&Qb[l15 * HEAD_DIM + dc * 32 + lg * 8];

  f32x4 oacc[16] = {};
  float m = -1e30f, l = 0.f;

  const bf16* Ksrc = Kp + (size_t)bkv * SEQ * HEAD_DIM;
  const bf16* Vsrc = VT + (size_t)bkv * HEAD_DIM * SEQ;

  for (int kb = kb0; kb < kb1; ++kb) {
    const int kbase = kb * 64;
    __syncthreads();
    #pragma unroll
    for (int i = 0; i < 8; ++i) {
      int id = i * 256 + tid;
      int row = id >> 5, ch = id & 31;
      int sc = ch ^ (row & 7);
      __builtin_amdgcn_global_load_lds(
          (const __attribute__((address_space(1))) void*)(Ksrc + (size_t)(kbase + row) * HEAD_DIM + sc * 8),
          (__attribute__((address_space(3))) void*)(Ks + id * 8), 16, 0, 0);
    }
    #pragma unroll
    for (int i = 0; i < 8; ++i) {
      int id = i * 256 + tid;
      int row = id >> 3, ch = id & 7;
      int sc = ch ^ (row & 7);
      __builtin_amdgcn_global_load_lds(
          (const __attribute__((address_space(1))) void*)(Vsrc + (size_t)row * SEQ + kbase + sc * 8),
          (__attribute__((address_space(3))) void*)(Vs + id * 8), 16, 0, 0);
    }
    __syncthreads();

    f32x4 sacc[4] = {};
    #pragma unroll
    for (int j = 0; j < 4; ++j) {
      const bf16* kl = &Ks[(j * 16 + l15) * HEAD_DIM];
      #pragma unroll
      for (int dc = 0; dc < 8; ++dc) {
        int ch = (dc * 4 + lg) ^ (l15 & 7);
        bf16x8 kf = *(const bf16x8*)&kl[ch * 8];
        sacc[j] = mfma16(kf, qf[dc], sacc[j]);
      }
    }

    float px[4][4];
    const bool need_mask = (kbase + 63 > q0);
    #pragma unroll
    for (int j = 0; j < 4; ++j)
      #pragma unroll
      for (int r = 0; r < 4; ++r) {
        float v = sacc[j][r] * 0.0625f;
        if (need_mask) {
          int kcol = kbase + j * 16 + lg * 4 + r;
          v = (kcol <= q0 + l15) ? v : -1e30f;
        }
        px[j][r] = v;
      }

    float mx = px[0][0];
    #pragma unroll
    for (int j = 0; j < 4; ++j)
      #pragma unroll
      for (int r = 0; r < 4; ++r) mx = fmaxf(mx, px[j][r]);
    mx = fmaxf(mx, __shfl_xor(mx, 16));
    mx = fmaxf(mx, __shfl_xor(mx, 32));
    float mnew = fmaxf(m, mx);
    float alpha = __expf(m - mnew);
    m = mnew;
    float s = 0.f;
    #pragma unroll
    for (int j = 0; j < 4; ++j) {
      bf16x4 pk;
      #pragma unroll
      for (int r = 0; r < 4; ++r) {
        float e = __expf(px[j][r] - mnew);
        s += e;
        pk[r] = (bf16)e;
      }
      *(bf16x4*)&pbuf[w][l15][j * 16 + lg * 4] = pk;
    }
    s += __shfl_xor(s, 16);
    s += __shfl_xor(s, 32);
    l = l * alpha + s;

    float ar[4];
    #pragma unroll
    for (int r = 0; r < 4; ++r) ar[r] = __shfl(alpha, lg * 4 + r);
    #pragma unroll
    for (int ni = 0; ni < 16; ++ni)
      #pragma unroll
      for (int r = 0; r < 4; ++r) oacc[ni][r] *= ar[r];

    bf16x8 pa0 = *(const bf16x8*)&pbuf[w][l15][lg * 8];
    bf16x8 pa1 = *(const bf16x8*)&pbuf[w][l15][32 + lg * 8];
    #pragma unroll
    for (int ni = 0; ni < 16; ++ni) {
      const bf16* vb = &Vs[(ni * 16 + l15) * 64];
      int c0 = lg ^ (l15 & 7);
      int c1 = (4 + lg) ^ (l15 & 7);
      bf16x8 v0 = *(const bf16x8*)&vb[c0 * 8];
      bf16x8 v1 = *(const bf16x8*)&vb[c1 * 8];
      oacc[ni] = mfma16(pa0, v0, oacc[ni]);
      oacc[ni] = mfma16(pa1, v1, oacc[ni]);
    }
  }

  bf16* Ob = Opart + ((size_t)cid * 64 + w * 16) * HEAD_DIM;
  #pragma unroll
  for (int ni = 0; ni < 16; ++ni)
    #pragma unroll
    for (int r = 0; r < 4; ++r)
      Ob[(size_t)(lg * 4 + r) * HEAD_DIM + ni * 16 + l15] = (bf16)oacc[ni][r];
  if (lg == 0) {
    ML[((size_t)cid * 64 + w * 16 + l15) * 2]     = m;
    ML[((size_t)cid * 64 + w * 16 + l15) * 2 + 1] = l;
  }
}

// ---------------- merge partials -> ao (b, s, h*256+d) bf16 ----------------
__global__ __launch_bounds__(256) void flash_merge(const bf16* __restrict__ Opart,
                                                   const float* __restrict__ ML,
                                                   bf16* __restrict__ AO) {
  const int bh = blockIdx.x, qt = blockIdx.y;
  const int b = bh >> 3, h = bh & 7;
  int cbase, nc;
  if (qt < 8)       { cbase = qt;                nc = 1; }
  else if (qt < 16) { cbase = 8  + 2 * (qt - 8);  nc = 2; }
  else if (qt < 24) { cbase = 24 + 3 * (qt - 16); nc = 3; }
  else              { cbase = 48 + 4 * (qt - 24); nc = 4; }
  const int cid0 = bh * CHUNKS_PER_BH + cbase;

  const int tid = threadIdx.x;
  const int row = tid >> 2, dseg = (tid & 3) * 64;

  float mi[4], li[4];
  float M = -1e30f;
  for (int i = 0; i < nc; ++i) {
    mi[i] = ML[((size_t)(cid0 + i) * 64 + row) * 2];
    li[i] = ML[((size_t)(cid0 + i) * 64 + row) * 2 + 1];
    M = fmaxf(M, mi[i]);
  }
  float wgt[4], L = 0.f;
  for (int i = 0; i < nc; ++i) {
    wgt[i] = __expf(mi[i] - M);
    L += li[i] * wgt[i];
  }
  const float inv = 1.0f / L;

  bf16* dst = AO + ((size_t)(b * SEQ + qt * 64 + row)) * 2048 + h * HEAD_DIM + dseg;
  for (int dv = 0; dv < 8; ++dv) {
    float acc[8] = {};
    for (int i = 0; i < nc; ++i) {
      bf16x8 o = *(const bf16x8*)&Opart[((size_t)(cid0 + i) * 64 + row) * HEAD_DIM + dseg + dv * 8];
      #pragma unroll
      for (int e = 0; e < 8; ++e) acc[e] += wgt[i] * (float)o[e];
    }
    bf16x8 ov;
    #pragma unroll
    for (int e = 0; e < 8; ++e) ov[e] = (bf16)(acc[e] * inv);
    *(bf16x8*)&dst[dv * 8] = ov;
  }
}

// ---------------- launch ----------------
extern "C" void kernel_launch(void* const* d_in, const int* in_sizes, int n_in,
                              void* d_out, int out_size, void* d_ws, size_t ws_size,
                              hipStream_t stream) {
  const float* hs = (const float*)d_in[0];
  const float* Wq = (const float*)d_in[3];
  const float* Wk = (const float*)d_in[4];
  const float* Wv = (const float*)d_in[5];
  const float* Wo = (const float*)d_in[6];
  float* out = (float*)d_out;

  char* ws = (char*)d_ws;
  bf16* hsb  = (bf16*)(ws);                    // 4096x5120        (41,943,040 B)
  bf16* wqkv = (bf16*)(ws + 41943040);         // 4096x5120        (41,943,040 B)
  bf16* qkv  = (bf16*)(ws + 83886080);         // 4096x4096        (33,554,432 B)
  bf16* qr   = (bf16*)(ws + 117440512);        // 2x8x2048x256     (16,777,216 B)
  bf16* kr   = (bf16*)(ws + 134217728);        // 2x4x2048x256     ( 8,388,608 B)
  bf16* vt   = (bf16*)(ws + 142606336);        // 2x4x256x2048     ( 8,388,608 B)
  bf16* ao   = (bf16*)(ws + 150994944);        // 4096x2048        (16,777,216 B)
  bf16* wob  = (bf16*)(ws + 167772160);        // 2560x2048        (10,485,760 B)
  bf16*  opart = (bf16*)(ws);                  // overlay (dead after gemm1)
  float* ml    = (float*)(ws + 41943040);

  hipFuncSetAttribute((const void*)&gemm_pipe<bf16>,  hipFuncAttributeMaxDynamicSharedMemorySize, 131072);
  hipFuncSetAttribute((const void*)&gemm_pipe<float>, hipFuncAttributeMaxDynamicSharedMemorySize, 131072);

  // fused casts: 47,185,920 elems / 2048 per block = 23040 blocks
  cast_all<<<23040, 256, 0, stream>>>(hs, Wq, Wk, Wv, Wo, (bf16*)ws, wob);

  // QKV projection: (4096x5120) @ (4096x5120)^T -> 4096x4096, grid 16x16=256 wg
  gemm_pipe<bf16><<<dim3(NQKV / 256, ROWS / 256), 512, 131072, stream>>>(hsb, wqkv, qkv, ROWS, NQKV, IND);

  rope_reorder<<<dim3(ROWS, 12), 128, 0, stream>>>(qkv, qr, kr);
  v_transpose<<<dim3(128, BATCH * NKV), 256, 0, stream>>>(qkv, vt);

  flash_attn<<<dim3(16 * CHUNKS_PER_BH), 256, 0, stream>>>(qr, kr, vt, opart, ml);
  flash_merge<<<dim3(16, 32), 256, 0, stream>>>(opart, ml, ao);

  // output projection: (4096x2048) @ (2560x2048)^T -> 4096x2560 fp32, grid 10x16=160 wg
  gemm_pipe<float><<<dim3(HID / 256, ROWS / 256), 512, 131072, stream>>>(ao, wob, out, ROWS, HID, 2048);
}